// Round 3
// baseline (1666.981 us; speedup 1.0000x reference)
//
#include <hip/hip_runtime.h>
#include <hip/hip_bf16.h>
#include <cstdint>
#include <cstddef>

#define NN   50000
#define NE   400000
#define DIN  128
#define DH   512
#define NCLS 128

#define NEG_INF (-__builtin_inff())

struct alignas(8) bf4 { __hip_bfloat16 v[4]; };

// ---------------- zero an int buffer ----------------
__launch_bounds__(256)
__global__ void k_zero(int* __restrict__ p, int n) {
  int i = blockIdx.x * 256 + threadIdx.x;
  if (i < n) p[i] = 0;
}

// ---------------- edge weights + in-degree histogram ----------------
__launch_bounds__(256)
__global__ void k_ew_hist(const int* __restrict__ src, const int* __restrict__ dst,
                          const float* __restrict__ pos, float* __restrict__ ew,
                          int* __restrict__ deg) {
  int e = blockIdx.x * 256 + threadIdx.x;
  if (e >= NE) return;
  int s = src[e], d = dst[e];
  ew[e] = 1.0f / (pos[s] - pos[d]);
  atomicAdd(&deg[d], 1);
}

// ---------------- exclusive scan over NN degrees (1 block) ----------------
__launch_bounds__(256)
__global__ void k_scan(const int* __restrict__ deg, int* __restrict__ rowptr, int n) {
  __shared__ int warp_sums[4];
  __shared__ int s_carry;
  int tid = threadIdx.x;
  if (tid == 0) s_carry = 0;
  __syncthreads();
  for (int base = 0; base < n; base += 256) {
    int idx = base + tid;
    int v = (idx < n) ? deg[idx] : 0;
    int xinc = v;
    #pragma unroll
    for (int o = 1; o < 64; o <<= 1) {
      int t = __shfl_up(xinc, o);
      if ((tid & 63) >= o) xinc += t;
    }
    int wid = tid >> 6;
    if ((tid & 63) == 63) warp_sums[wid] = xinc;
    __syncthreads();
    int woff = 0;
    #pragma unroll
    for (int w = 0; w < 4; ++w) if (w < wid) woff += warp_sums[w];
    int incl = xinc + woff + s_carry;
    if (idx < n) rowptr[idx] = incl - v;
    __syncthreads();
    if (tid == 255) s_carry = incl;
    __syncthreads();
  }
  if (tid == 0) rowptr[n] = s_carry;
}

// ---------------- scatter edge ids into CSR ----------------
__launch_bounds__(256)
__global__ void k_scatter(const int* __restrict__ dst, const int* __restrict__ rowptr,
                          int* __restrict__ cnt, int* __restrict__ perm) {
  int e = blockIdx.x * 256 + threadIdx.x;
  if (e >= NE) return;
  int d = dst[e];
  int p = atomicAdd(&cnt[d], 1);
  perm[rowptr[d] + p] = e;
}

// ---------------- layer-1 aggregation: agg1[n,d] = max_e x[src_e,d]*ew_e (bf16 out) ----
__launch_bounds__(128)
__global__ void k_agg1(const int* __restrict__ src, const float* __restrict__ ew,
                       const int* __restrict__ rowptr, const int* __restrict__ perm,
                       const float* __restrict__ x, __hip_bfloat16* __restrict__ agg) {
  int n = blockIdx.x;
  int d = threadIdx.x;                 // 0..127
  int beg = rowptr[n], end = rowptr[n + 1];
  float m = NEG_INF;
  for (int i = beg; i < end; ++i) {
    int e = perm[i];
    int s = src[e];
    float w = ew[e];
    m = fmaxf(m, x[(size_t)s * DIN + d] * w);
  }
  if (beg == end) m = 0.0f;            // PyG: empty segments -> 0
  agg[(size_t)n * DIN + d] = __float2bfloat16(m);
}

// ---------------- layer-2 aggregation over 512 bf16 features ----------------
__launch_bounds__(256)
__global__ void k_agg2(const int* __restrict__ src, const float* __restrict__ ew,
                       const int* __restrict__ rowptr, const int* __restrict__ perm,
                       const __hip_bfloat16* __restrict__ h, __hip_bfloat16* __restrict__ agg) {
  int n = blockIdx.x;
  int t = threadIdx.x;                 // features 2t, 2t+1
  int beg = rowptr[n], end = rowptr[n + 1];
  float m0 = NEG_INF, m1 = NEG_INF;
  for (int i = beg; i < end; ++i) {
    int e = perm[i];
    int s = src[e];
    float w = ew[e];
    __hip_bfloat162 v = *(const __hip_bfloat162*)(h + (size_t)s * DH + 2 * t);
    float2 f = __bfloat1622float2(v);
    m0 = fmaxf(m0, f.x * w);
    m1 = fmaxf(m1, f.y * w);
  }
  if (beg == end) { m0 = 0.0f; m1 = 0.0f; }
  *(__hip_bfloat162*)(agg + (size_t)n * DH + 2 * t) =
      __float22bfloat162_rn(make_float2(m0, m1));
}

// ---------------- fused dual GEMM + bias + LayerNorm + ReLU -> bf16 ----------------
// C[m,:] = LN( A0[m,:]@W0^T + A1[m,:]@W1^T + brel ) * g + b, relu, bf16 store.
// A ops: bf16 (Ab) or fp32 (Af) selected by non-null Af. W: [DH, K] fp32. BN = DH = 512.
#define GBM 32
#define GBK 16

__launch_bounds__(256)
__global__ void k_gemm_ln(const __hip_bfloat16* __restrict__ A0b, const float* __restrict__ A0f,
                          const float* __restrict__ W0,
                          const __hip_bfloat16* __restrict__ A1b, const float* __restrict__ A1f,
                          const float* __restrict__ W1,
                          const float* __restrict__ brel, const float* __restrict__ gvec,
                          const float* __restrict__ bvec,
                          __hip_bfloat16* __restrict__ out, int K) {
  __shared__ float As[GBK][GBM + 1];
  __shared__ float Ws[GBK][DH];
  int tid = threadIdx.x;
  int m0 = blockIdx.x * GBM;
  int rg = tid >> 6;                   // wave id 0..3 -> rows rg*8..+7
  int lane = tid & 63;
  int lane4 = lane * 4;                // cols lane4..+3 and 256+lane4..+3

  float acc[8][8];
  #pragma unroll
  for (int i = 0; i < 8; ++i)
    #pragma unroll
    for (int j = 0; j < 8; ++j) acc[i][j] = 0.0f;

  int skk = tid & 15;                  // k within tile
  int smm = tid >> 4;                  // row pair id

  for (int pass = 0; pass < 2; ++pass) {
    const __hip_bfloat16* __restrict__ Ab = pass ? A1b : A0b;
    const float* __restrict__ Af = pass ? A1f : A0f;
    const float* __restrict__ W  = pass ? W1  : W0;
    for (int k0 = 0; k0 < K; k0 += GBK) {
      // stage A tile (32 x 16)
      #pragma unroll
      for (int r = 0; r < 2; ++r) {
        int m = smm * 2 + r;
        int gm = m0 + m;
        float v = 0.0f;
        if (gm < NN) {
          size_t idx = (size_t)gm * K + k0 + skk;
          v = Af ? Af[idx] : __bfloat162float(Ab[idx]);
        }
        As[skk][m] = v;
      }
      // stage W tile (16 x 512), 2 weight rows per thread
      #pragma unroll
      for (int r = 0; r < 2; ++r) {
        int n = tid * 2 + r;
        const float* wr = W + (size_t)n * K + k0;
        float4 w0 = *(const float4*)(wr + 0);
        float4 w1 = *(const float4*)(wr + 4);
        float4 w2 = *(const float4*)(wr + 8);
        float4 w3 = *(const float4*)(wr + 12);
        Ws[0][n] = w0.x;  Ws[1][n] = w0.y;  Ws[2][n] = w0.z;  Ws[3][n] = w0.w;
        Ws[4][n] = w1.x;  Ws[5][n] = w1.y;  Ws[6][n] = w1.z;  Ws[7][n] = w1.w;
        Ws[8][n] = w2.x;  Ws[9][n] = w2.y;  Ws[10][n] = w2.z; Ws[11][n] = w2.w;
        Ws[12][n] = w3.x; Ws[13][n] = w3.y; Ws[14][n] = w3.z; Ws[15][n] = w3.w;
      }
      __syncthreads();
      #pragma unroll
      for (int k = 0; k < GBK; ++k) {
        float a[8];
        #pragma unroll
        for (int i = 0; i < 8; ++i) a[i] = As[k][rg * 8 + i];
        float4 b0 = *(const float4*)&Ws[k][lane4];
        float4 b1 = *(const float4*)&Ws[k][256 + lane4];
        float b[8] = {b0.x, b0.y, b0.z, b0.w, b1.x, b1.y, b1.z, b1.w};
        #pragma unroll
        for (int i = 0; i < 8; ++i)
          #pragma unroll
          for (int j = 0; j < 8; ++j) acc[i][j] += a[i] * b[j];
      }
      __syncthreads();
    }
  }

  // epilogue: + brel, LayerNorm over 512 (wave-local), *g + b, ReLU, bf16 store
  float4 br0 = *(const float4*)&brel[lane4];
  float4 br1 = *(const float4*)&brel[256 + lane4];
  float4 gg0 = *(const float4*)&gvec[lane4];
  float4 gg1 = *(const float4*)&gvec[256 + lane4];
  float4 be0 = *(const float4*)&bvec[lane4];
  float4 be1 = *(const float4*)&bvec[256 + lane4];
  float brv[8] = {br0.x, br0.y, br0.z, br0.w, br1.x, br1.y, br1.z, br1.w};
  float gv[8]  = {gg0.x, gg0.y, gg0.z, gg0.w, gg1.x, gg1.y, gg1.z, gg1.w};
  float bev[8] = {be0.x, be0.y, be0.z, be0.w, be1.x, be1.y, be1.z, be1.w};

  #pragma unroll
  for (int i = 0; i < 8; ++i) {
    int gm = m0 + rg * 8 + i;          // wave-uniform
    float v[8];
    float s = 0.0f, ss = 0.0f;
    #pragma unroll
    for (int j = 0; j < 8; ++j) {
      v[j] = acc[i][j] + brv[j];
      s += v[j];
      ss += v[j] * v[j];
    }
    #pragma unroll
    for (int o = 32; o; o >>= 1) {
      s  += __shfl_xor(s, o);
      ss += __shfl_xor(ss, o);
    }
    float mean = s * (1.0f / DH);
    float var  = ss * (1.0f / DH) - mean * mean;
    float rs = rsqrtf(var + 1e-5f);
    if (gm < NN) {
      bf4 o0, o1;
      #pragma unroll
      for (int j = 0; j < 4; ++j)
        o0.v[j] = __float2bfloat16(fmaxf((v[j] - mean) * rs * gv[j] + bev[j], 0.0f));
      #pragma unroll
      for (int j = 0; j < 4; ++j)
        o1.v[j] = __float2bfloat16(fmaxf((v[4 + j] - mean) * rs * gv[4 + j] + bev[4 + j], 0.0f));
      *(bf4*)(out + (size_t)gm * DH + lane4) = o0;
      *(bf4*)(out + (size_t)gm * DH + 256 + lane4) = o1;
    }
  }
}

// ---------------- classifier GEMM: out = h2 @ Wcls^T + bcls (fp32 out) ----------------
#define CBM 64
#define CBN 128
#define CBK 16

__launch_bounds__(256)
__global__ void k_cls(const __hip_bfloat16* __restrict__ A, const float* __restrict__ W,
                      const float* __restrict__ bias, float* __restrict__ C) {
  __shared__ float As[CBK][CBM + 4];
  __shared__ float Bs[CBK][CBN + 4];
  int tid = threadIdx.x;
  int tm = tid >> 4;
  int tn = tid & 15;
  int m0 = blockIdx.x * CBM;

  float acc[4][8];
  #pragma unroll
  for (int i = 0; i < 4; ++i)
    #pragma unroll
    for (int j = 0; j < 8; ++j) acc[i][j] = 0.0f;

  int lk = tid & 15;
  int lr = tid >> 4;
  for (int k0 = 0; k0 < DH; k0 += CBK) {
    #pragma unroll
    for (int i = 0; i < 4; ++i) {
      int m = lr + i * 16;
      int gm = m0 + m;
      As[lk][m] = (gm < NN) ? __bfloat162float(A[(size_t)gm * DH + k0 + lk]) : 0.0f;
    }
    #pragma unroll
    for (int i = 0; i < 8; ++i) {
      int j = lr + i * 16;
      Bs[lk][j] = W[(size_t)j * DH + k0 + lk];
    }
    __syncthreads();
    #pragma unroll
    for (int k = 0; k < CBK; ++k) {
      float a[4], bb[8];
      #pragma unroll
      for (int i = 0; i < 4; ++i) a[i] = As[k][tm * 4 + i];
      #pragma unroll
      for (int j = 0; j < 4; ++j) bb[j] = Bs[k][tn * 4 + j];
      #pragma unroll
      for (int j = 0; j < 4; ++j) bb[4 + j] = Bs[k][64 + tn * 4 + j];
      #pragma unroll
      for (int i = 0; i < 4; ++i)
        #pragma unroll
        for (int j = 0; j < 8; ++j) acc[i][j] += a[i] * bb[j];
    }
    __syncthreads();
  }
  #pragma unroll
  for (int i = 0; i < 4; ++i) {
    int gm = m0 + tm * 4 + i;
    if (gm >= NN) continue;
    #pragma unroll
    for (int jh = 0; jh < 2; ++jh) {
      int gc = jh * 64 + tn * 4;
      float4 v;
      v.x = acc[i][jh * 4 + 0] + bias[gc + 0];
      v.y = acc[i][jh * 4 + 1] + bias[gc + 1];
      v.z = acc[i][jh * 4 + 2] + bias[gc + 2];
      v.w = acc[i][jh * 4 + 3] + bias[gc + 3];
      *(float4*)(C + (size_t)gm * NCLS + gc) = v;
    }
  }
}

extern "C" void kernel_launch(void* const* d_in, const int* in_sizes, int n_in,
                              void* d_out, int out_size, void* d_ws, size_t ws_size,
                              hipStream_t stream) {
  (void)in_sizes; (void)n_in; (void)out_size; (void)ws_size;
  const float* x      = (const float*)d_in[0];
  const int*   ei     = (const int*)  d_in[1];
  const float* pos    = (const float*)d_in[2];
  const float* Wrel1  = (const float*)d_in[3];
  const float* brel1  = (const float*)d_in[4];
  const float* Wroot1 = (const float*)d_in[5];
  const float* g1     = (const float*)d_in[6];
  const float* b1     = (const float*)d_in[7];
  const float* Wrel2  = (const float*)d_in[8];
  const float* brel2  = (const float*)d_in[9];
  const float* Wroot2 = (const float*)d_in[10];
  const float* g2     = (const float*)d_in[11];
  const float* b2     = (const float*)d_in[12];
  const float* Wcls   = (const float*)d_in[13];
  const float* bcls   = (const float*)d_in[14];
  const int* src = ei;           // edge_index[0]
  const int* dst = ei + NE;      // edge_index[1]
  float* out = (float*)d_out;

  char* ws = (char*)d_ws;
  size_t off = 0;
  auto alloc = [&](size_t bytes) -> void* {
    void* p = ws + off;
    off += (bytes + 255) & ~(size_t)255;
    return p;
  };
  // total ~118.8 MB
  float*           ew     = (float*)          alloc((size_t)NE * 4);
  int*             rowptr = (int*)            alloc((size_t)(NN + 1) * 4);
  int*             cnt    = (int*)            alloc((size_t)NN * 4);
  int*             perm   = (int*)            alloc((size_t)NE * 4);
  __hip_bfloat16*  agg1   = (__hip_bfloat16*) alloc((size_t)NN * DIN * 2);
  __hip_bfloat16*  h1     = (__hip_bfloat16*) alloc((size_t)NN * DH * 2);
  __hip_bfloat16*  agg2   = (__hip_bfloat16*) alloc((size_t)NN * DH * 2);
  __hip_bfloat16*  h2     = agg2;   // layer-2 GEMM writes in place over agg2

  // ---- CSR build ----
  k_zero<<<(NN + 255) / 256, 256, 0, stream>>>(cnt, NN);
  k_ew_hist<<<(NE + 255) / 256, 256, 0, stream>>>(src, dst, pos, ew, cnt);
  k_scan<<<1, 256, 0, stream>>>(cnt, rowptr, NN);
  k_zero<<<(NN + 255) / 256, 256, 0, stream>>>(cnt, NN);
  k_scatter<<<(NE + 255) / 256, 256, 0, stream>>>(dst, rowptr, cnt, perm);

  int gblocks = (NN + GBM - 1) / GBM;

  // ---- layer 1 ----
  k_agg1<<<NN, DIN, 0, stream>>>(src, ew, rowptr, perm, x, agg1);
  k_gemm_ln<<<gblocks, 256, 0, stream>>>(agg1, nullptr, Wrel1,
                                         nullptr, x, Wroot1,
                                         brel1, g1, b1, h1, DIN);
  // ---- layer 2 ----
  k_agg2<<<NN, 256, 0, stream>>>(src, ew, rowptr, perm, h1, agg2);
  k_gemm_ln<<<gblocks, 256, 0, stream>>>(agg2, nullptr, Wrel2,
                                         h1, nullptr, Wroot2,
                                         brel2, g2, b2, h2, DH);
  // ---- classifier ----
  k_cls<<<(NN + CBM - 1) / CBM, 256, 0, stream>>>(h2, Wcls, bcls, out);
}

// Round 4
// 866.078 us; speedup vs baseline: 1.9247x; 1.9247x over previous
//
#include <hip/hip_runtime.h>
#include <hip/hip_bf16.h>
#include <cstdint>
#include <cstddef>

#define NN   50000
#define NE   400000
#define DIN  128
#define DH   512
#define NCLS 128

#define NEG_INF (-__builtin_inff())

typedef short short8_t __attribute__((ext_vector_type(8)));
typedef float f32x4   __attribute__((ext_vector_type(4)));

static __device__ inline short f2bf(float f) {
  __hip_bfloat16 h = __float2bfloat16(f);
  return *reinterpret_cast<short*>(&h);
}

// ---------------- zero an int buffer ----------------
__launch_bounds__(256)
__global__ void k_zero(int* __restrict__ p, int n) {
  int i = blockIdx.x * 256 + threadIdx.x;
  if (i < n) p[i] = 0;
}

// ---------------- pack fp32 weight [N][K] -> bf16 K-panels P[kb][n][32] ----------------
__launch_bounds__(256)
__global__ void k_pack_w(const float* __restrict__ W, short* __restrict__ P,
                         int N, int K) {
  int id = blockIdx.x * 256 + threadIdx.x;
  int total = N * K;
  if (id >= total) return;
  int kb  = id / (N * 32);
  int rem = id % (N * 32);
  int n   = rem / 32;
  int kk  = rem % 32;
  P[id] = f2bf(W[(size_t)n * K + kb * 32 + kk]);
}

// ---------------- edge weights + in-degree histogram ----------------
__launch_bounds__(256)
__global__ void k_ew_hist(const int* __restrict__ src, const int* __restrict__ dst,
                          const float* __restrict__ pos, float* __restrict__ ew,
                          int* __restrict__ deg) {
  int e = blockIdx.x * 256 + threadIdx.x;
  if (e >= NE) return;
  int s = src[e], d = dst[e];
  ew[e] = 1.0f / (pos[s] - pos[d]);
  atomicAdd(&deg[d], 1);
}

// ---------------- exclusive scan over NN degrees (1 block) ----------------
__launch_bounds__(256)
__global__ void k_scan(const int* __restrict__ deg, int* __restrict__ rowptr, int n) {
  __shared__ int warp_sums[4];
  __shared__ int s_carry;
  int tid = threadIdx.x;
  if (tid == 0) s_carry = 0;
  __syncthreads();
  for (int base = 0; base < n; base += 256) {
    int idx = base + tid;
    int v = (idx < n) ? deg[idx] : 0;
    int xinc = v;
    #pragma unroll
    for (int o = 1; o < 64; o <<= 1) {
      int t = __shfl_up(xinc, o);
      if ((tid & 63) >= o) xinc += t;
    }
    int wid = tid >> 6;
    if ((tid & 63) == 63) warp_sums[wid] = xinc;
    __syncthreads();
    int woff = 0;
    #pragma unroll
    for (int w = 0; w < 4; ++w) if (w < wid) woff += warp_sums[w];
    int incl = xinc + woff + s_carry;
    if (idx < n) rowptr[idx] = incl - v;
    __syncthreads();
    if (tid == 255) s_carry = incl;
    __syncthreads();
  }
  if (tid == 0) rowptr[n] = s_carry;
}

// ---------------- scatter edge ids into CSR ----------------
__launch_bounds__(256)
__global__ void k_scatter(const int* __restrict__ dst, const int* __restrict__ rowptr,
                          int* __restrict__ cnt, int* __restrict__ perm) {
  int e = blockIdx.x * 256 + threadIdx.x;
  if (e >= NE) return;
  int d = dst[e];
  int p = atomicAdd(&cnt[d], 1);
  perm[rowptr[d] + p] = e;
}

// ---------------- layer-1 aggregation: agg1[n,d] = max_e x[src_e,d]*ew_e (bf16 out) ----
__launch_bounds__(128)
__global__ void k_agg1(const int* __restrict__ src, const float* __restrict__ ew,
                       const int* __restrict__ rowptr, const int* __restrict__ perm,
                       const float* __restrict__ x, __hip_bfloat16* __restrict__ agg) {
  int n = blockIdx.x;
  int d = threadIdx.x;                 // 0..127
  int beg = rowptr[n], end = rowptr[n + 1];
  float m = NEG_INF;
  for (int i = beg; i < end; ++i) {
    int e = perm[i];
    int s = src[e];
    float w = ew[e];
    m = fmaxf(m, x[(size_t)s * DIN + d] * w);
  }
  if (beg == end) m = 0.0f;            // PyG: empty segments -> 0
  agg[(size_t)n * DIN + d] = __float2bfloat16(m);
}

// ---------------- layer-2 aggregation over 512 bf16 features ----------------
__launch_bounds__(256)
__global__ void k_agg2(const int* __restrict__ src, const float* __restrict__ ew,
                       const int* __restrict__ rowptr, const int* __restrict__ perm,
                       const __hip_bfloat16* __restrict__ h, __hip_bfloat16* __restrict__ agg) {
  int n = blockIdx.x;
  int t = threadIdx.x;                 // features 2t, 2t+1
  int beg = rowptr[n], end = rowptr[n + 1];
  float m0 = NEG_INF, m1 = NEG_INF;
  for (int i = beg; i < end; ++i) {
    int e = perm[i];
    int s = src[e];
    float w = ew[e];
    __hip_bfloat162 v = *(const __hip_bfloat162*)(h + (size_t)s * DH + 2 * t);
    float2 f = __bfloat1622float2(v);
    m0 = fmaxf(m0, f.x * w);
    m1 = fmaxf(m1, f.y * w);
  }
  if (beg == end) { m0 = 0.0f; m1 = 0.0f; }
  *(__hip_bfloat162*)(agg + (size_t)n * DH + 2 * t) =
      __float22bfloat162_rn(make_float2(m0, m1));
}

// ============== MFMA fused dual GEMM + bias + LayerNorm + ReLU -> bf16 ==============
// out[m,:] = relu( LN( A0[m,:]@W0^T + A1[m,:]@W1^T + brel ) * g + b ), bf16.
// A: [M,K] bf16 (Ab) or fp32 (Af). P0/P1: packed bf16 panels P[kb][n(0..511)][32].
// Tile: BM=32 rows x BN=512 cols (full row), BK=32, 256 threads = 4 waves,
// wave w owns cols w*128..+127 => 2x8 fragments of 16x16, mfma_f32_16x16x32_bf16.
#define TBM 32

__launch_bounds__(256)
__global__ void k_mfma_ln(const __hip_bfloat16* __restrict__ A0b, const float* __restrict__ A0f,
                          const short* __restrict__ P0,
                          const __hip_bfloat16* __restrict__ A1b, const float* __restrict__ A1f,
                          const short* __restrict__ P1,
                          const float* __restrict__ brel, const float* __restrict__ gvec,
                          const float* __restrict__ bvec,
                          __hip_bfloat16* __restrict__ out, int K) {
  __shared__ short As[TBM][40];        // 2.5 KB (pad 40: 80B rows, rotates banks)
  __shared__ short Bs[DH][40];         // 40 KB
  __shared__ float red_s[4][TBM];
  __shared__ float red_ss[4][TBM];

  int tid  = threadIdx.x;
  int wave = tid >> 6;
  int lane = tid & 63;
  int lhi  = lane >> 4;                // k-block / row-quad selector
  int llo  = lane & 15;                // fragment row (A) / col (B,D)
  int wcol0 = wave * 128;
  int m0 = blockIdx.x * TBM;

  f32x4 acc[2][8];
  #pragma unroll
  for (int i = 0; i < 2; ++i)
    #pragma unroll
    for (int c = 0; c < 8; ++c) acc[i][c] = (f32x4){0.f, 0.f, 0.f, 0.f};

  int a_row = tid >> 2;                // 0..63 (only <32 used)
  int a_chk = tid & 3;

  for (int pass = 0; pass < 2; ++pass) {
    const __hip_bfloat16* __restrict__ Ab = pass ? A1b : A0b;
    const float* __restrict__ Af = pass ? A1f : A0f;
    const short* __restrict__ P  = pass ? P1  : P0;
    for (int kb = 0; kb < K / 32; ++kb) {
      int k0 = kb * 32;
      // ---- stage A tile 32x32 (threads 0..127) ----
      if (tid < 128) {
        int gm = m0 + a_row;
        short8_t av = (short8_t)0;
        if (gm < NN) {
          if (Af) {
            const float* p = Af + (size_t)gm * K + k0 + a_chk * 8;
            float4 f0 = *(const float4*)p;
            float4 f1 = *(const float4*)(p + 4);
            av[0] = f2bf(f0.x); av[1] = f2bf(f0.y); av[2] = f2bf(f0.z); av[3] = f2bf(f0.w);
            av[4] = f2bf(f1.x); av[5] = f2bf(f1.y); av[6] = f2bf(f1.z); av[7] = f2bf(f1.w);
          } else {
            av = *(const short8_t*)((const short*)Ab + (size_t)gm * K + k0 + a_chk * 8);
          }
        }
        *(short8_t*)&As[a_row][a_chk * 8] = av;
      }
      // ---- stage B panel 512x32 (contiguous 32 KB in global) ----
      const short* panel = P + (size_t)kb * DH * 32;
      #pragma unroll
      for (int u = 0; u < 8; ++u) {
        short8_t wv = *(const short8_t*)(panel + tid * 64 + u * 8);
        int n  = tid * 2 + (u >> 2);
        int kk = (u & 3) * 8;
        *(short8_t*)&Bs[n][kk] = wv;
      }
      __syncthreads();
      // ---- 16 MFMAs ----
      short8_t a0 = *(const short8_t*)&As[llo][lhi * 8];
      short8_t a1 = *(const short8_t*)&As[16 + llo][lhi * 8];
      #pragma unroll
      for (int c = 0; c < 8; ++c) {
        short8_t bfr = *(const short8_t*)&Bs[wcol0 + c * 16 + llo][lhi * 8];
        acc[0][c] = __builtin_amdgcn_mfma_f32_16x16x32_bf16(a0, bfr, acc[0][c], 0, 0, 0);
        acc[1][c] = __builtin_amdgcn_mfma_f32_16x16x32_bf16(a1, bfr, acc[1][c], 0, 0, 0);
      }
      __syncthreads();
    }
  }

  // ---- epilogue: bias, LN (cross-wave), scale/shift, relu, bf16 store ----
  float brv[8], gv[8], bev[8];
  #pragma unroll
  for (int c = 0; c < 8; ++c) {
    int col = wcol0 + c * 16 + llo;
    brv[c] = brel[col];
    gv[c]  = gvec[col];
    bev[c] = bvec[col];
  }
  float s[2][4], ss[2][4];
  #pragma unroll
  for (int ri = 0; ri < 2; ++ri)
    #pragma unroll
    for (int r = 0; r < 4; ++r) {
      float t = 0.f, tt = 0.f;
      #pragma unroll
      for (int c = 0; c < 8; ++c) {
        float v = acc[ri][c][r] + brv[c];
        t += v; tt += v * v;
      }
      #pragma unroll
      for (int o = 1; o < 16; o <<= 1) {
        t  += __shfl_xor(t, o);
        tt += __shfl_xor(tt, o);
      }
      s[ri][r] = t; ss[ri][r] = tt;
    }
  if (llo == 0) {
    #pragma unroll
    for (int ri = 0; ri < 2; ++ri)
      #pragma unroll
      for (int r = 0; r < 4; ++r) {
        int row = ri * 16 + lhi * 4 + r;
        red_s[wave][row]  = s[ri][r];
        red_ss[wave][row] = ss[ri][r];
      }
  }
  __syncthreads();
  #pragma unroll
  for (int ri = 0; ri < 2; ++ri)
    #pragma unroll
    for (int r = 0; r < 4; ++r) {
      int row = ri * 16 + lhi * 4 + r;
      float S = 0.f, SS = 0.f;
      #pragma unroll
      for (int w = 0; w < 4; ++w) { S += red_s[w][row]; SS += red_ss[w][row]; }
      float mean = S * (1.0f / DH);
      float var  = SS * (1.0f / DH) - mean * mean;
      float rs = rsqrtf(var + 1e-5f);
      int gm = m0 + row;
      if (gm < NN) {
        #pragma unroll
        for (int c = 0; c < 8; ++c) {
          float v = acc[ri][c][r] + brv[c];
          float o = fmaxf((v - mean) * rs * gv[c] + bev[c], 0.0f);
          out[(size_t)gm * DH + wcol0 + c * 16 + llo] = __float2bfloat16(o);
        }
      }
    }
}

// ============== MFMA classifier GEMM: out = h2 @ Wcls^T + bcls (fp32) ==============
// Tile: BM=64 x BN=128 (full), BK=32. 4 waves; wave w owns cols w*32..+31.
#define CBM 64

__launch_bounds__(256)
__global__ void k_mfma_cls(const __hip_bfloat16* __restrict__ A, const short* __restrict__ P,
                           const float* __restrict__ bias, float* __restrict__ C) {
  __shared__ short As[CBM][40];        // 5 KB
  __shared__ short Bs[NCLS][40];       // 10 KB

  int tid  = threadIdx.x;
  int wave = tid >> 6;
  int lane = tid & 63;
  int lhi  = lane >> 4;
  int llo  = lane & 15;
  int wcol0 = wave * 32;
  int m0 = blockIdx.x * CBM;

  f32x4 acc[4][2];
  #pragma unroll
  for (int i = 0; i < 4; ++i)
    #pragma unroll
    for (int c = 0; c < 2; ++c) acc[i][c] = (f32x4){0.f, 0.f, 0.f, 0.f};

  int a_row = tid >> 2;                // 0..63
  int a_chk = tid & 3;

  for (int kb = 0; kb < DH / 32; ++kb) {
    int k0 = kb * 32;
    { // stage A 64x32
      int gm = m0 + a_row;
      short8_t av = (short8_t)0;
      if (gm < NN)
        av = *(const short8_t*)((const short*)A + (size_t)gm * DH + k0 + a_chk * 8);
      *(short8_t*)&As[a_row][a_chk * 8] = av;
    }
    { // stage B panel 128x32 (8 KB contiguous)
      const short* panel = P + (size_t)kb * NCLS * 32;
      int n  = tid >> 1;
      int kk = (tid & 1) * 16;
      *(short8_t*)&Bs[n][kk]     = *(const short8_t*)(panel + tid * 16);
      *(short8_t*)&Bs[n][kk + 8] = *(const short8_t*)(panel + tid * 16 + 8);
    }
    __syncthreads();
    short8_t a[4];
    #pragma unroll
    for (int ri = 0; ri < 4; ++ri)
      a[ri] = *(const short8_t*)&As[ri * 16 + llo][lhi * 8];
    #pragma unroll
    for (int c = 0; c < 2; ++c) {
      short8_t bfr = *(const short8_t*)&Bs[wcol0 + c * 16 + llo][lhi * 8];
      #pragma unroll
      for (int ri = 0; ri < 4; ++ri)
        acc[ri][c] = __builtin_amdgcn_mfma_f32_16x16x32_bf16(a[ri], bfr, acc[ri][c], 0, 0, 0);
    }
    __syncthreads();
  }

  #pragma unroll
  for (int c = 0; c < 2; ++c) {
    int col = wcol0 + c * 16 + llo;
    float bc = bias[col];
    #pragma unroll
    for (int ri = 0; ri < 4; ++ri)
      #pragma unroll
      for (int r = 0; r < 4; ++r) {
        int gm = m0 + ri * 16 + lhi * 4 + r;
        if (gm < NN) C[(size_t)gm * NCLS + col] = acc[ri][c][r] + bc;
      }
  }
}

extern "C" void kernel_launch(void* const* d_in, const int* in_sizes, int n_in,
                              void* d_out, int out_size, void* d_ws, size_t ws_size,
                              hipStream_t stream) {
  (void)in_sizes; (void)n_in; (void)out_size; (void)ws_size;
  const float* x      = (const float*)d_in[0];
  const int*   ei     = (const int*)  d_in[1];
  const float* pos    = (const float*)d_in[2];
  const float* Wrel1  = (const float*)d_in[3];
  const float* brel1  = (const float*)d_in[4];
  const float* Wroot1 = (const float*)d_in[5];
  const float* g1     = (const float*)d_in[6];
  const float* b1     = (const float*)d_in[7];
  const float* Wrel2  = (const float*)d_in[8];
  const float* brel2  = (const float*)d_in[9];
  const float* Wroot2 = (const float*)d_in[10];
  const float* g2     = (const float*)d_in[11];
  const float* b2     = (const float*)d_in[12];
  const float* Wcls   = (const float*)d_in[13];
  const float* bcls   = (const float*)d_in[14];
  const int* src = ei;           // edge_index[0]
  const int* dst = ei + NE;      // edge_index[1]
  float* out = (float*)d_out;

  char* ws = (char*)d_ws;
  size_t off = 0;
  auto alloc = [&](size_t bytes) -> void* {
    void* p = ws + off;
    off += (bytes + 255) & ~(size_t)255;
    return p;
  };
  // ~121.3 MB total
  float*           ew     = (float*)          alloc((size_t)NE * 4);
  int*             rowptr = (int*)            alloc((size_t)(NN + 1) * 4);
  int*             cnt    = (int*)            alloc((size_t)NN * 4);
  int*             perm   = (int*)            alloc((size_t)NE * 4);
  __hip_bfloat16*  agg1   = (__hip_bfloat16*) alloc((size_t)NN * DIN * 2);
  __hip_bfloat16*  h1     = (__hip_bfloat16*) alloc((size_t)NN * DH * 2);
  __hip_bfloat16*  agg2   = (__hip_bfloat16*) alloc((size_t)NN * DH * 2);
  __hip_bfloat16*  h2     = agg2;   // layer-2 GEMM writes in place over agg2
  short*           Pr1    = (short*)alloc((size_t)DH * DIN * 2);    // Wrel1 panels
  short*           Pq1    = (short*)alloc((size_t)DH * DIN * 2);    // Wroot1 panels
  short*           Pr2    = (short*)alloc((size_t)DH * DH * 2);     // Wrel2 panels
  short*           Pq2    = (short*)alloc((size_t)DH * DH * 2);     // Wroot2 panels
  short*           Pc     = (short*)alloc((size_t)NCLS * DH * 2);   // Wcls panels

  // ---- weight packing (bf16 K-panels) ----
  k_pack_w<<<(DH * DIN + 255) / 256, 256, 0, stream>>>(Wrel1,  Pr1, DH,   DIN);
  k_pack_w<<<(DH * DIN + 255) / 256, 256, 0, stream>>>(Wroot1, Pq1, DH,   DIN);
  k_pack_w<<<(DH * DH  + 255) / 256, 256, 0, stream>>>(Wrel2,  Pr2, DH,   DH);
  k_pack_w<<<(DH * DH  + 255) / 256, 256, 0, stream>>>(Wroot2, Pq2, DH,   DH);
  k_pack_w<<<(NCLS * DH + 255) / 256, 256, 0, stream>>>(Wcls,  Pc,  NCLS, DH);

  // ---- CSR build ----
  k_zero<<<(NN + 255) / 256, 256, 0, stream>>>(cnt, NN);
  k_ew_hist<<<(NE + 255) / 256, 256, 0, stream>>>(src, dst, pos, ew, cnt);
  k_scan<<<1, 256, 0, stream>>>(cnt, rowptr, NN);
  k_zero<<<(NN + 255) / 256, 256, 0, stream>>>(cnt, NN);
  k_scatter<<<(NE + 255) / 256, 256, 0, stream>>>(dst, rowptr, cnt, perm);

  int gblocks = (NN + TBM - 1) / TBM;

  // ---- layer 1 ----
  k_agg1<<<NN, DIN, 0, stream>>>(src, ew, rowptr, perm, x, agg1);
  k_mfma_ln<<<gblocks, 256, 0, stream>>>(agg1, nullptr, Pr1,
                                         nullptr, x, Pq1,
                                         brel1, g1, b1, h1, DIN);
  // ---- layer 2 ----
  k_agg2<<<NN, 256, 0, stream>>>(src, ew, rowptr, perm, h1, agg2);
  k_mfma_ln<<<gblocks, 256, 0, stream>>>(agg2, nullptr, Pr2,
                                         h1, nullptr, Pq2,
                                         brel2, g2, b2, h2, DH);
  // ---- classifier ----
  k_mfma_cls<<<(NN + CBM - 1) / CBM, 256, 0, stream>>>(h2, Pc, bcls, out);
}

// Round 7
// 627.312 us; speedup vs baseline: 2.6573x; 1.3806x over previous
//
#include <hip/hip_runtime.h>
#include <hip/hip_bf16.h>
#include <cstdint>
#include <cstddef>

#define NN   50000
#define NE   400000
#define DIN  128
#define DH   512
#define NCLS 128

#define NEG_INF (-__builtin_inff())

typedef short short8_t __attribute__((ext_vector_type(8)));
typedef float f32x4   __attribute__((ext_vector_type(4)));

typedef const __attribute__((address_space(1))) void* gas_t;
typedef __attribute__((address_space(3))) void* las_t;

// DMA 16B/lane: LDS dest = wave-uniform base + lane*16 (linear); global src per-lane.
static __device__ inline void load_lds16(const void* g, void* l) {
  __builtin_amdgcn_global_load_lds((gas_t)g, (las_t)l, 16, 0, 0);
}

// chunk swizzle (involution): LDS slot L <-> global chunk g
static __device__ inline int swz(int L) {
  return (L & ~3) | ((L & 3) ^ ((L >> 3) & 3));
}

static __device__ inline short f2bf(float f) {
  __hip_bfloat16 h = __float2bfloat16(f);
  return *reinterpret_cast<short*>(&h);
}

// ---------------- zero an int buffer ----------------
__launch_bounds__(256)
__global__ void k_zero(int* __restrict__ p, int n) {
  int i = blockIdx.x * 256 + threadIdx.x;
  if (i < n) p[i] = 0;
}

// ---------------- x fp32 -> bf16 (row-major unchanged) ----------------
__launch_bounds__(256)
__global__ void k_cvt_x(const float* __restrict__ x, short* __restrict__ xb) {
  int i = blockIdx.x * 256 + threadIdx.x;
  if ((size_t)i * 8 >= (size_t)NN * DIN) return;
  float4 f0 = *(const float4*)(x + (size_t)i * 8);
  float4 f1 = *(const float4*)(x + (size_t)i * 8 + 4);
  short8_t v;
  v[0] = f2bf(f0.x); v[1] = f2bf(f0.y); v[2] = f2bf(f0.z); v[3] = f2bf(f0.w);
  v[4] = f2bf(f1.x); v[5] = f2bf(f1.y); v[6] = f2bf(f1.z); v[7] = f2bf(f1.w);
  *(short8_t*)(xb + (size_t)i * 8) = v;
}

// ---------------- pack fp32 weight [N][K] -> bf16 K-panels P[kb][n][32] ----------------
__launch_bounds__(256)
__global__ void k_pack_w(const float* __restrict__ W, short* __restrict__ P,
                         int N, int K) {
  int id = blockIdx.x * 256 + threadIdx.x;
  int total = N * K;
  if (id >= total) return;
  int kb  = id / (N * 32);
  int rem = id % (N * 32);
  int n   = rem / 32;
  int kk  = rem % 32;
  P[id] = f2bf(W[(size_t)n * K + kb * 32 + kk]);
}

// ---------------- edge weights + in-degree histogram ----------------
__launch_bounds__(256)
__global__ void k_ew_hist(const int* __restrict__ src, const int* __restrict__ dst,
                          const float* __restrict__ pos, float* __restrict__ ew,
                          int* __restrict__ deg) {
  int e = blockIdx.x * 256 + threadIdx.x;
  if (e >= NE) return;
  int s = src[e], d = dst[e];
  ew[e] = 1.0f / (pos[s] - pos[d]);
  atomicAdd(&deg[d], 1);
}

// ---------------- exclusive scan over NN degrees (1 block) ----------------
__launch_bounds__(256)
__global__ void k_scan(const int* __restrict__ deg, int* __restrict__ rowptr, int n) {
  __shared__ int warp_sums[4];
  __shared__ int s_carry;
  int tid = threadIdx.x;
  if (tid == 0) s_carry = 0;
  __syncthreads();
  for (int base = 0; base < n; base += 256) {
    int idx = base + tid;
    int v = (idx < n) ? deg[idx] : 0;
    int xinc = v;
    #pragma unroll
    for (int o = 1; o < 64; o <<= 1) {
      int t = __shfl_up(xinc, o);
      if ((tid & 63) >= o) xinc += t;
    }
    int wid = tid >> 6;
    if ((tid & 63) == 63) warp_sums[wid] = xinc;
    __syncthreads();
    int woff = 0;
    #pragma unroll
    for (int w = 0; w < 4; ++w) if (w < wid) woff += warp_sums[w];
    int incl = xinc + woff + s_carry;
    if (idx < n) rowptr[idx] = incl - v;
    __syncthreads();
    if (tid == 255) s_carry = incl;
    __syncthreads();
  }
  if (tid == 0) rowptr[n] = s_carry;
}

// ---------------- scatter edge ids into CSR ----------------
__launch_bounds__(256)
__global__ void k_scatter(const int* __restrict__ dst, const int* __restrict__ rowptr,
                          int* __restrict__ cnt, int* __restrict__ perm) {
  int e = blockIdx.x * 256 + threadIdx.x;
  if (e >= NE) return;
  int d = dst[e];
  int p = atomicAdd(&cnt[d], 1);
  perm[rowptr[d] + p] = e;
}

// ---------------- layer-1 aggregation: agg1[n,d] = max_e x[src_e,d]*ew_e (bf16 out) ----
__launch_bounds__(128)
__global__ void k_agg1(const int* __restrict__ src, const float* __restrict__ ew,
                       const int* __restrict__ rowptr, const int* __restrict__ perm,
                       const float* __restrict__ x, __hip_bfloat16* __restrict__ agg) {
  int n = blockIdx.x;
  int d = threadIdx.x;                 // 0..127
  int beg = rowptr[n], end = rowptr[n + 1];
  float m = NEG_INF;
  for (int i = beg; i < end; ++i) {
    int e = perm[i];
    int s = src[e];
    float w = ew[e];
    m = fmaxf(m, x[(size_t)s * DIN + d] * w);
  }
  if (beg == end) m = 0.0f;            // PyG: empty segments -> 0
  agg[(size_t)n * DIN + d] = __float2bfloat16(m);
}

// ---------------- layer-2 aggregation over 512 bf16 features ----------------
__launch_bounds__(256)
__global__ void k_agg2(const int* __restrict__ src, const float* __restrict__ ew,
                       const int* __restrict__ rowptr, const int* __restrict__ perm,
                       const __hip_bfloat16* __restrict__ h, __hip_bfloat16* __restrict__ agg) {
  int n = blockIdx.x;
  int t = threadIdx.x;                 // features 2t, 2t+1
  int beg = rowptr[n], end = rowptr[n + 1];
  float m0 = NEG_INF, m1 = NEG_INF;
  for (int i = beg; i < end; ++i) {
    int e = perm[i];
    int s = src[e];
    float w = ew[e];
    __hip_bfloat162 v = *(const __hip_bfloat162*)(h + (size_t)s * DH + 2 * t);
    float2 f = __bfloat1622float2(v);
    m0 = fmaxf(m0, f.x * w);
    m1 = fmaxf(m1, f.y * w);
  }
  if (beg == end) { m0 = 0.0f; m1 = 0.0f; }
  *(__hip_bfloat162*)(agg + (size_t)n * DH + 2 * t) =
      __float22bfloat162_rn(make_float2(m0, m1));
}

// ============== MFMA fused dual GEMM + bias + LayerNorm + ReLU -> bf16 ==============
// out[m,:] = relu( LN( A0[m,:]@W0^T + A1[m,:]@W1^T + brel ) * g + b ), bf16.
// A0/A1: [M,K] bf16 row-major. P0/P1: packed bf16 panels P[kb][n(0..511)][32].
// Tile: BM=64 x BN=512 (full row). 512 threads = 8 waves; wave w owns cols w*64..+63.
// Staging: global_load_lds dwordx4, linear LDS + involution-swizzled global source;
// ds_read_b128 fragments use the same swizzle -> conflict-free both sides.
#define TBM 64

__launch_bounds__(512)
__global__ void k_mfma_ln(const short* __restrict__ A0, const short* __restrict__ P0,
                          const short* __restrict__ A1, const short* __restrict__ P1,
                          const float* __restrict__ brel, const float* __restrict__ gvec,
                          const float* __restrict__ bvec,
                          __hip_bfloat16* __restrict__ out, int K) {
  __shared__ __align__(16) short Bs[DH * 32];    // 32 KB
  __shared__ __align__(16) short As[TBM * 32];   // 4 KB
  __shared__ float2 red[8][TBM];                 // 4 KB

  int tid  = threadIdx.x;
  int wave = tid >> 6;                 // 0..7
  int lane = tid & 63;
  int lhi  = lane >> 4;                // k-chunk selector
  int llo  = lane & 15;                // fragment row (A) / col (B,D)
  int wcol0 = wave * 64;
  int m0 = blockIdx.x * TBM;

  f32x4 acc[4][4];
  #pragma unroll
  for (int ri = 0; ri < 4; ++ri)
    #pragma unroll
    for (int c = 0; c < 4; ++c) acc[ri][c] = (f32x4){0.f, 0.f, 0.f, 0.f};

  for (int pass = 0; pass < 2; ++pass) {
    const short* __restrict__ Aop = pass ? A1 : A0;
    const short* __restrict__ P   = pass ? P1 : P0;
    int nkb = K >> 5;
    for (int kb = 0; kb < nkb; ++kb) {
      // ---- A tile 64x32 = 256 chunks: 1 DMA issue on waves 0..3 ----
      if (wave < 4) {
        int L = wave * 64 + lane;
        int g = swz(L);
        int n = g >> 2, c4 = g & 3;
        int gm = m0 + n; if (gm >= NN) gm = NN - 1;
        load_lds16(Aop + (size_t)gm * K + kb * 32 + c4 * 8,
                   (char*)As + wave * 1024);
      }
      // ---- B panel 512x32 = 2048 chunks: 4 DMA issues per wave ----
      const short* __restrict__ panel = P + (size_t)kb * (DH * 32);
      #pragma unroll
      for (int u = 0; u < 4; ++u) {
        int L = wave * 256 + u * 64 + lane;
        int g = swz(L);
        load_lds16(panel + (size_t)g * 8, (char*)Bs + (wave * 256 + u * 64) * 16);
      }
      __syncthreads();                 // drains vmcnt -> DMA complete
      // ---- fragments + 16 MFMAs ----
      short8_t a[4];
      #pragma unroll
      for (int ri = 0; ri < 4; ++ri) {
        int n = ri * 16 + llo;
        int slot = n * 4 + (lhi ^ ((n >> 1) & 3));
        a[ri] = *(const short8_t*)(As + slot * 8);
      }
      #pragma unroll
      for (int c = 0; c < 4; ++c) {
        int n = wcol0 + c * 16 + llo;
        int slot = n * 4 + (lhi ^ ((n >> 1) & 3));
        short8_t bfr = *(const short8_t*)(Bs + slot * 8);
        #pragma unroll
        for (int ri = 0; ri < 4; ++ri)
          acc[ri][c] = __builtin_amdgcn_mfma_f32_16x16x32_bf16(a[ri], bfr, acc[ri][c], 0, 0, 0);
      }
      __syncthreads();
    }
  }

  // ---- epilogue: bias, LN (cross-wave via LDS), scale/shift, relu, bf16 store ----
  float brv[4], gv[4], bev[4];
  #pragma unroll
  for (int c = 0; c < 4; ++c) {
    int col = wcol0 + c * 16 + llo;
    brv[c] = brel[col];
    gv[c]  = gvec[col];
    bev[c] = bvec[col];
  }
  #pragma unroll
  for (int ri = 0; ri < 4; ++ri)
    #pragma unroll
    for (int r = 0; r < 4; ++r) {
      float t = 0.f, tt = 0.f;
      #pragma unroll
      for (int c = 0; c < 4; ++c) {
        float v = acc[ri][c][r] + brv[c];
        t += v; tt += v * v;
      }
      #pragma unroll
      for (int o = 1; o < 16; o <<= 1) {
        t  += __shfl_xor(t, o);
        tt += __shfl_xor(tt, o);
      }
      if (llo == 0) red[wave][ri * 16 + lhi * 4 + r] = make_float2(t, tt);
    }
  __syncthreads();
  if (tid < TBM) {
    float S = 0.f, SS = 0.f;
    #pragma unroll
    for (int w = 0; w < 8; ++w) { float2 p = red[w][tid]; S += p.x; SS += p.y; }
    float mean = S * (1.0f / DH);
    float var  = SS * (1.0f / DH) - mean * mean;
    red[0][tid] = make_float2(mean, rsqrtf(var + 1e-5f));
  }
  __syncthreads();
  #pragma unroll
  for (int ri = 0; ri < 4; ++ri)
    #pragma unroll
    for (int r = 0; r < 4; ++r) {
      int row = ri * 16 + lhi * 4 + r;
      int gm = m0 + row;
      if (gm < NN) {
        float2 mr = red[0][row];
        #pragma unroll
        for (int c = 0; c < 4; ++c) {
          float v = acc[ri][c][r] + brv[c];
          float o = fmaxf((v - mr.x) * mr.y * gv[c] + bev[c], 0.0f);
          out[(size_t)gm * DH + wcol0 + c * 16 + llo] = __float2bfloat16(o);
        }
      }
    }
}

// ============== MFMA classifier GEMM: out = h2 @ Wcls^T + bcls (fp32) ==============
// BM=64 x BN=128, BK=32, 256 threads = 4 waves; wave w owns cols w*32..+31.
#define CBM 64

__launch_bounds__(256)
__global__ void k_mfma_cls(const short* __restrict__ A, const short* __restrict__ P,
                           const float* __restrict__ bias, float* __restrict__ C) {
  __shared__ __align__(16) short Bs[NCLS * 32];  // 8 KB
  __shared__ __align__(16) short As[CBM * 32];   // 4 KB

  int tid  = threadIdx.x;
  int wave = tid >> 6;
  int lane = tid & 63;
  int lhi  = lane >> 4;
  int llo  = lane & 15;
  int wcol0 = wave * 32;
  int m0 = blockIdx.x * CBM;

  f32x4 acc[4][2];
  #pragma unroll
  for (int ri = 0; ri < 4; ++ri)
    #pragma unroll
    for (int c = 0; c < 2; ++c) acc[ri][c] = (f32x4){0.f, 0.f, 0.f, 0.f};

  for (int kb = 0; kb < DH / 32; ++kb) {
    { // A tile 64x32 = 256 chunks: 1 issue per wave
      int L = wave * 64 + lane;
      int g = swz(L);
      int n = g >> 2, c4 = g & 3;
      int gm = m0 + n; if (gm >= NN) gm = NN - 1;
      load_lds16(A + (size_t)gm * DH + kb * 32 + c4 * 8, (char*)As + wave * 1024);
    }
    { // B panel 128x32 = 512 chunks: 2 issues per wave
      const short* __restrict__ panel = P + (size_t)kb * (NCLS * 32);
      #pragma unroll
      for (int u = 0; u < 2; ++u) {
        int L = wave * 128 + u * 64 + lane;
        int g = swz(L);
        load_lds16(panel + (size_t)g * 8, (char*)Bs + (wave * 128 + u * 64) * 16);
      }
    }
    __syncthreads();
    short8_t a[4];
    #pragma unroll
    for (int ri = 0; ri < 4; ++ri) {
      int n = ri * 16 + llo;
      int slot = n * 4 + (lhi ^ ((n >> 1) & 3));
      a[ri] = *(const short8_t*)(As + slot * 8);
    }
    #pragma unroll
    for (int c = 0; c < 2; ++c) {
      int n = wcol0 + c * 16 + llo;
      int slot = n * 4 + (lhi ^ ((n >> 1) & 3));
      short8_t bfr = *(const short8_t*)(Bs + slot * 8);
      #pragma unroll
      for (int ri = 0; ri < 4; ++ri)
        acc[ri][c] = __builtin_amdgcn_mfma_f32_16x16x32_bf16(a[ri], bfr, acc[ri][c], 0, 0, 0);
    }
    __syncthreads();
  }

  #pragma unroll
  for (int c = 0; c < 2; ++c) {
    int col = wcol0 + c * 16 + llo;
    float bc = bias[col];
    #pragma unroll
    for (int ri = 0; ri < 4; ++ri)
      #pragma unroll
      for (int r = 0; r < 4; ++r) {
        int gm = m0 + ri * 16 + lhi * 4 + r;
        if (gm < NN) C[(size_t)gm * NCLS + col] = acc[ri][c][r] + bc;
      }
  }
}

extern "C" void kernel_launch(void* const* d_in, const int* in_sizes, int n_in,
                              void* d_out, int out_size, void* d_ws, size_t ws_size,
                              hipStream_t stream) {
  (void)in_sizes; (void)n_in; (void)out_size; (void)ws_size;
  const float* x      = (const float*)d_in[0];
  const int*   ei     = (const int*)  d_in[1];
  const float* pos    = (const float*)d_in[2];
  const float* Wrel1  = (const float*)d_in[3];
  const float* brel1  = (const float*)d_in[4];
  const float* Wroot1 = (const float*)d_in[5];
  const float* g1     = (const float*)d_in[6];
  const float* b1     = (const float*)d_in[7];
  const float* Wrel2  = (const float*)d_in[8];
  const float* brel2  = (const float*)d_in[9];
  const float* Wroot2 = (const float*)d_in[10];
  const float* g2     = (const float*)d_in[11];
  const float* b2     = (const float*)d_in[12];
  const float* Wcls   = (const float*)d_in[13];
  const float* bcls   = (const float*)d_in[14];
  const int* src = ei;           // edge_index[0]
  const int* dst = ei + NE;      // edge_index[1]
  float* out = (float*)d_out;

  char* ws = (char*)d_ws;
  size_t off = 0;
  auto alloc = [&](size_t bytes) -> void* {
    void* p = ws + off;
    off += (bytes + 255) & ~(size_t)255;
    return p;
  };
  // ~121.3 MB total (xb aliases agg2: dead until after layer-1 GEMM)
  float*           ew     = (float*)          alloc((size_t)NE * 4);
  int*             rowptr = (int*)            alloc((size_t)(NN + 1) * 4);
  int*             cnt    = (int*)            alloc((size_t)NN * 4);
  int*             perm   = (int*)            alloc((size_t)NE * 4);
  __hip_bfloat16*  agg1   = (__hip_bfloat16*) alloc((size_t)NN * DIN * 2);
  __hip_bfloat16*  h1     = (__hip_bfloat16*) alloc((size_t)NN * DH * 2);
  __hip_bfloat16*  agg2   = (__hip_bfloat16*) alloc((size_t)NN * DH * 2);
  __hip_bfloat16*  h2     = agg2;             // layer-2 GEMM writes in place
  short*           xb     = (short*)agg2;     // bf16 x, overlaps agg2 (see ordering)
  short*           Pr1    = (short*)alloc((size_t)DH * DIN * 2);
  short*           Pq1    = (short*)alloc((size_t)DH * DIN * 2);
  short*           Pr2    = (short*)alloc((size_t)DH * DH * 2);
  short*           Pq2    = (short*)alloc((size_t)DH * DH * 2);
  short*           Pc     = (short*)alloc((size_t)NCLS * DH * 2);

  // ---- weight packing + x conversion ----
  k_pack_w<<<(DH * DIN + 255) / 256, 256, 0, stream>>>(Wrel1,  Pr1, DH,   DIN);
  k_pack_w<<<(DH * DIN + 255) / 256, 256, 0, stream>>>(Wroot1, Pq1, DH,   DIN);
  k_pack_w<<<(DH * DH  + 255) / 256, 256, 0, stream>>>(Wrel2,  Pr2, DH,   DH);
  k_pack_w<<<(DH * DH  + 255) / 256, 256, 0, stream>>>(Wroot2, Pq2, DH,   DH);
  k_pack_w<<<(NCLS * DH + 255) / 256, 256, 0, stream>>>(Wcls,  Pc,  NCLS, DH);
  k_cvt_x<<<(NN * DIN / 8 + 255) / 256, 256, 0, stream>>>(x, xb);

  // ---- CSR build ----
  k_zero<<<(NN + 255) / 256, 256, 0, stream>>>(cnt, NN);
  k_ew_hist<<<(NE + 255) / 256, 256, 0, stream>>>(src, dst, pos, ew, cnt);
  k_scan<<<1, 256, 0, stream>>>(cnt, rowptr, NN);
  k_zero<<<(NN + 255) / 256, 256, 0, stream>>>(cnt, NN);
  k_scatter<<<(NE + 255) / 256, 256, 0, stream>>>(dst, rowptr, cnt, perm);

  int gblocks = (NN + TBM - 1) / TBM;

  // ---- layer 1 ----
  k_agg1<<<NN, DIN, 0, stream>>>(src, ew, rowptr, perm, x, agg1);
  k_mfma_ln<<<gblocks, 512, 0, stream>>>((const short*)agg1, Pr1,
                                         xb, Pq1,
                                         brel1, g1, b1, h1, DIN);
  // ---- layer 2 (xb dead from here; agg2 reuses its space) ----
  k_agg2<<<NN, 256, 0, stream>>>(src, ew, rowptr, perm, h1, agg2);
  k_mfma_ln<<<gblocks, 512, 0, stream>>>((const short*)agg2, Pr2,
                                         (const short*)h1, Pq2,
                                         brel2, g2, b2, h2, DH);
  // ---- classifier ----
  k_mfma_cls<<<(NN + CBM - 1) / CBM, 256, 0, stream>>>((const short*)h2, Pc, bcls, out);
}

// Round 8
// 511.341 us; speedup vs baseline: 3.2600x; 1.2268x over previous
//
#include <hip/hip_runtime.h>
#include <hip/hip_bf16.h>
#include <cstdint>
#include <cstddef>

#define NN   50000
#define NE   400000
#define DIN  128
#define DH   512
#define NCLS 128

#define NEG_INF (-__builtin_inff())

typedef short short8_t __attribute__((ext_vector_type(8)));
typedef float f32x4   __attribute__((ext_vector_type(4)));

typedef const __attribute__((address_space(1))) void* gas_t;
typedef __attribute__((address_space(3))) void* las_t;

// DMA 16B/lane: LDS dest = wave-uniform base + lane*16 (linear); global src per-lane.
static __device__ inline void load_lds16(const void* g, void* l) {
  __builtin_amdgcn_global_load_lds((gas_t)g, (las_t)l, 16, 0, 0);
}

// chunk swizzle (involution): LDS slot L <-> global chunk g
static __device__ inline int swz(int L) {
  return (L & ~3) | ((L & 3) ^ ((L >> 3) & 3));
}

static __device__ inline short f2bf(float f) {
  __hip_bfloat16 h = __float2bfloat16(f);
  return *reinterpret_cast<short*>(&h);
}

static __device__ inline float bf2f(short s) {
  unsigned int u = ((unsigned int)(unsigned short)s) << 16;
  return __uint_as_float(u);
}

// ---------------- zero an int buffer ----------------
__launch_bounds__(256)
__global__ void k_zero(int* __restrict__ p, int n) {
  int i = blockIdx.x * 256 + threadIdx.x;
  if (i < n) p[i] = 0;
}

// ---------------- x fp32 -> bf16 (row-major unchanged) ----------------
__launch_bounds__(256)
__global__ void k_cvt_x(const float* __restrict__ x, short* __restrict__ xb) {
  int i = blockIdx.x * 256 + threadIdx.x;
  if ((size_t)i * 8 >= (size_t)NN * DIN) return;
  float4 f0 = *(const float4*)(x + (size_t)i * 8);
  float4 f1 = *(const float4*)(x + (size_t)i * 8 + 4);
  short8_t v;
  v[0] = f2bf(f0.x); v[1] = f2bf(f0.y); v[2] = f2bf(f0.z); v[3] = f2bf(f0.w);
  v[4] = f2bf(f1.x); v[5] = f2bf(f1.y); v[6] = f2bf(f1.z); v[7] = f2bf(f1.w);
  *(short8_t*)(xb + (size_t)i * 8) = v;
}

// ---------------- pack fp32 weight [N][K] -> bf16 K-panels P[kb][n][32] ----------------
__launch_bounds__(256)
__global__ void k_pack_w(const float* __restrict__ W, short* __restrict__ P,
                         int N, int K) {
  int id = blockIdx.x * 256 + threadIdx.x;
  int total = N * K;
  if (id >= total) return;
  int kb  = id / (N * 32);
  int rem = id % (N * 32);
  int n   = rem / 32;
  int kk  = rem % 32;
  P[id] = f2bf(W[(size_t)n * K + kb * 32 + kk]);
}

// ---------------- edge weights + in-degree histogram ----------------
__launch_bounds__(256)
__global__ void k_ew_hist(const int* __restrict__ src, const int* __restrict__ dst,
                          const float* __restrict__ pos, float* __restrict__ ew,
                          int* __restrict__ deg) {
  int e = blockIdx.x * 256 + threadIdx.x;
  if (e >= NE) return;
  int s = src[e], d = dst[e];
  ew[e] = 1.0f / (pos[s] - pos[d]);
  atomicAdd(&deg[d], 1);
}

// ---------------- exclusive scan over NN degrees (1 block) ----------------
__launch_bounds__(256)
__global__ void k_scan(const int* __restrict__ deg, int* __restrict__ rowptr, int n) {
  __shared__ int warp_sums[4];
  __shared__ int s_carry;
  int tid = threadIdx.x;
  if (tid == 0) s_carry = 0;
  __syncthreads();
  for (int base = 0; base < n; base += 256) {
    int idx = base + tid;
    int v = (idx < n) ? deg[idx] : 0;
    int xinc = v;
    #pragma unroll
    for (int o = 1; o < 64; o <<= 1) {
      int t = __shfl_up(xinc, o);
      if ((tid & 63) >= o) xinc += t;
    }
    int wid = tid >> 6;
    if ((tid & 63) == 63) warp_sums[wid] = xinc;
    __syncthreads();
    int woff = 0;
    #pragma unroll
    for (int w = 0; w < 4; ++w) if (w < wid) woff += warp_sums[w];
    int incl = xinc + woff + s_carry;
    if (idx < n) rowptr[idx] = incl - v;
    __syncthreads();
    if (tid == 255) s_carry = incl;
    __syncthreads();
  }
  if (tid == 0) rowptr[n] = s_carry;
}

// ---------------- scatter {src, ew} records into CSR slots ----------------
__launch_bounds__(256)
__global__ void k_scatter(const int* __restrict__ src, const int* __restrict__ dst,
                          const float* __restrict__ ew, const int* __restrict__ rowptr,
                          int* __restrict__ cnt, int2* __restrict__ glist) {
  int e = blockIdx.x * 256 + threadIdx.x;
  if (e >= NE) return;
  int d = dst[e];
  int p = atomicAdd(&cnt[d], 1);
  glist[rowptr[d] + p] = make_int2(src[e], __float_as_int(ew[e]));
}

// ---------------- layer-1 aggregation: wave/node, bf16 x rows (256B) ----------------
__launch_bounds__(256)
__global__ void k_agg1(const int* __restrict__ rowptr, const int2* __restrict__ glist,
                       const short* __restrict__ xb, __hip_bfloat16* __restrict__ agg) {
  int node = blockIdx.x * 4 + (threadIdx.x >> 6);
  int lane = threadIdx.x & 63;
  if (node >= NN) return;
  int beg = rowptr[node], end = rowptr[node + 1];
  float a0 = NEG_INF, a1 = NEG_INF;
  int i = beg;
  for (; i + 2 <= end; i += 2) {
    int2 m0 = glist[i], m1 = glist[i + 1];
    __hip_bfloat162 v0 = *(const __hip_bfloat162*)(xb + (size_t)m0.x * DIN + lane * 2);
    __hip_bfloat162 v1 = *(const __hip_bfloat162*)(xb + (size_t)m1.x * DIN + lane * 2);
    float w0 = __int_as_float(m0.y), w1 = __int_as_float(m1.y);
    float2 f0 = __bfloat1622float2(v0);
    float2 f1 = __bfloat1622float2(v1);
    a0 = fmaxf(a0, fmaxf(f0.x * w0, f1.x * w1));
    a1 = fmaxf(a1, fmaxf(f0.y * w0, f1.y * w1));
  }
  if (i < end) {
    int2 m0 = glist[i];
    __hip_bfloat162 v0 = *(const __hip_bfloat162*)(xb + (size_t)m0.x * DIN + lane * 2);
    float w0 = __int_as_float(m0.y);
    float2 f0 = __bfloat1622float2(v0);
    a0 = fmaxf(a0, f0.x * w0);
    a1 = fmaxf(a1, f0.y * w0);
  }
  if (beg == end) { a0 = 0.0f; a1 = 0.0f; }   // PyG: empty segments -> 0
  *(__hip_bfloat162*)(agg + (size_t)node * DIN + lane * 2) =
      __float22bfloat162_rn(make_float2(a0, a1));
}

// ---------------- layer-2 aggregation: wave/node, 16B/lane rows (1KB) ----------------
__launch_bounds__(256)
__global__ void k_agg2(const int* __restrict__ rowptr, const int2* __restrict__ glist,
                       const short* __restrict__ h, __hip_bfloat16* __restrict__ agg) {
  int node = blockIdx.x * 4 + (threadIdx.x >> 6);
  int lane = threadIdx.x & 63;
  if (node >= NN) return;
  int beg = rowptr[node], end = rowptr[node + 1];
  float acc[8];
  #pragma unroll
  for (int j = 0; j < 8; ++j) acc[j] = NEG_INF;
  int i = beg;
  for (; i + 2 <= end; i += 2) {
    int2 m0 = glist[i], m1 = glist[i + 1];
    short8_t v0 = *(const short8_t*)(h + (size_t)m0.x * DH + lane * 8);
    short8_t v1 = *(const short8_t*)(h + (size_t)m1.x * DH + lane * 8);
    float w0 = __int_as_float(m0.y), w1 = __int_as_float(m1.y);
    #pragma unroll
    for (int j = 0; j < 8; ++j)
      acc[j] = fmaxf(acc[j], fmaxf(bf2f(v0[j]) * w0, bf2f(v1[j]) * w1));
  }
  if (i < end) {
    int2 m0 = glist[i];
    short8_t v0 = *(const short8_t*)(h + (size_t)m0.x * DH + lane * 8);
    float w0 = __int_as_float(m0.y);
    #pragma unroll
    for (int j = 0; j < 8; ++j)
      acc[j] = fmaxf(acc[j], bf2f(v0[j]) * w0);
  }
  if (beg == end) {
    #pragma unroll
    for (int j = 0; j < 8; ++j) acc[j] = 0.0f;
  }
  short8_t o;
  #pragma unroll
  for (int j = 0; j < 8; ++j) o[j] = f2bf(acc[j]);
  *(short8_t*)((short*)agg + (size_t)node * DH + lane * 8) = o;
}

// ============== MFMA fused dual GEMM + bias + LayerNorm + ReLU -> bf16 ==============
// out[m,:] = relu( LN( A0[m,:]@W0^T + A1[m,:]@W1^T + brel ) * g + b ), bf16.
// A0/A1: [M,K] bf16 row-major. P0/P1: packed bf16 panels P[kb][n(0..511)][32].
// Tile: BM=64 x BN=512 (full row). 512 threads = 8 waves; wave w owns cols w*64..+63.
#define TBM 64

__launch_bounds__(512)
__global__ void k_mfma_ln(const short* __restrict__ A0, const short* __restrict__ P0,
                          const short* __restrict__ A1, const short* __restrict__ P1,
                          const float* __restrict__ brel, const float* __restrict__ gvec,
                          const float* __restrict__ bvec,
                          __hip_bfloat16* __restrict__ out, int K) {
  __shared__ __align__(16) short Bs[DH * 32];    // 32 KB
  __shared__ __align__(16) short As[TBM * 32];   // 4 KB
  __shared__ float2 red[8][TBM];                 // 4 KB

  int tid  = threadIdx.x;
  int wave = tid >> 6;                 // 0..7
  int lane = tid & 63;
  int lhi  = lane >> 4;                // k-chunk selector
  int llo  = lane & 15;                // fragment row (A) / col (B,D)
  int wcol0 = wave * 64;
  int m0 = blockIdx.x * TBM;

  f32x4 acc[4][4];
  #pragma unroll
  for (int ri = 0; ri < 4; ++ri)
    #pragma unroll
    for (int c = 0; c < 4; ++c) acc[ri][c] = (f32x4){0.f, 0.f, 0.f, 0.f};

  for (int pass = 0; pass < 2; ++pass) {
    const short* __restrict__ Aop = pass ? A1 : A0;
    const short* __restrict__ P   = pass ? P1 : P0;
    int nkb = K >> 5;
    for (int kb = 0; kb < nkb; ++kb) {
      // ---- A tile 64x32 = 256 chunks: 1 DMA issue on waves 0..3 ----
      if (wave < 4) {
        int L = wave * 64 + lane;
        int g = swz(L);
        int n = g >> 2, c4 = g & 3;
        int gm = m0 + n; if (gm >= NN) gm = NN - 1;
        load_lds16(Aop + (size_t)gm * K + kb * 32 + c4 * 8,
                   (char*)As + wave * 1024);
      }
      // ---- B panel 512x32 = 2048 chunks: 4 DMA issues per wave ----
      const short* __restrict__ panel = P + (size_t)kb * (DH * 32);
      #pragma unroll
      for (int u = 0; u < 4; ++u) {
        int L = wave * 256 + u * 64 + lane;
        int g = swz(L);
        load_lds16(panel + (size_t)g * 8, (char*)Bs + (wave * 256 + u * 64) * 16);
      }
      __syncthreads();                 // drains vmcnt -> DMA complete
      // ---- fragments + 16 MFMAs ----
      short8_t a[4];
      #pragma unroll
      for (int ri = 0; ri < 4; ++ri) {
        int n = ri * 16 + llo;
        int slot = n * 4 + (lhi ^ ((n >> 1) & 3));
        a[ri] = *(const short8_t*)(As + slot * 8);
      }
      #pragma unroll
      for (int c = 0; c < 4; ++c) {
        int n = wcol0 + c * 16 + llo;
        int slot = n * 4 + (lhi ^ ((n >> 1) & 3));
        short8_t bfr = *(const short8_t*)(Bs + slot * 8);
        #pragma unroll
        for (int ri = 0; ri < 4; ++ri)
          acc[ri][c] = __builtin_amdgcn_mfma_f32_16x16x32_bf16(a[ri], bfr, acc[ri][c], 0, 0, 0);
      }
      __syncthreads();
    }
  }

  // ---- epilogue: bias, LN (cross-wave via LDS), scale/shift, relu, bf16 store ----
  float brv[4], gv[4], bev[4];
  #pragma unroll
  for (int c = 0; c < 4; ++c) {
    int col = wcol0 + c * 16 + llo;
    brv[c] = brel[col];
    gv[c]  = gvec[col];
    bev[c] = bvec[col];
  }
  #pragma unroll
  for (int ri = 0; ri < 4; ++ri)
    #pragma unroll
    for (int r = 0; r < 4; ++r) {
      float t = 0.f, tt = 0.f;
      #pragma unroll
      for (int c = 0; c < 4; ++c) {
        float v = acc[ri][c][r] + brv[c];
        t += v; tt += v * v;
      }
      #pragma unroll
      for (int o = 1; o < 16; o <<= 1) {
        t  += __shfl_xor(t, o);
        tt += __shfl_xor(tt, o);
      }
      if (llo == 0) red[wave][ri * 16 + lhi * 4 + r] = make_float2(t, tt);
    }
  __syncthreads();
  if (tid < TBM) {
    float S = 0.f, SS = 0.f;
    #pragma unroll
    for (int w = 0; w < 8; ++w) { float2 p = red[w][tid]; S += p.x; SS += p.y; }
    float mean = S * (1.0f / DH);
    float var  = SS * (1.0f / DH) - mean * mean;
    red[0][tid] = make_float2(mean, rsqrtf(var + 1e-5f));
  }
  __syncthreads();
  #pragma unroll
  for (int ri = 0; ri < 4; ++ri)
    #pragma unroll
    for (int r = 0; r < 4; ++r) {
      int row = ri * 16 + lhi * 4 + r;
      int gm = m0 + row;
      if (gm < NN) {
        float2 mr = red[0][row];
        #pragma unroll
        for (int c = 0; c < 4; ++c) {
          float v = acc[ri][c][r] + brv[c];
          float o = fmaxf((v - mr.x) * mr.y * gv[c] + bev[c], 0.0f);
          out[(size_t)gm * DH + wcol0 + c * 16 + llo] = __float2bfloat16(o);
        }
      }
    }
}

// ============== MFMA classifier GEMM: out = h2 @ Wcls^T + bcls (fp32) ==============
// BM=64 x BN=128, BK=32, 256 threads = 4 waves; wave w owns cols w*32..+31.
#define CBM 64

__launch_bounds__(256)
__global__ void k_mfma_cls(const short* __restrict__ A, const short* __restrict__ P,
                           const float* __restrict__ bias, float* __restrict__ C) {
  __shared__ __align__(16) short Bs[NCLS * 32];  // 8 KB
  __shared__ __align__(16) short As[CBM * 32];   // 4 KB

  int tid  = threadIdx.x;
  int wave = tid >> 6;
  int lane = tid & 63;
  int lhi  = lane >> 4;
  int llo  = lane & 15;
  int wcol0 = wave * 32;
  int m0 = blockIdx.x * CBM;

  f32x4 acc[4][2];
  #pragma unroll
  for (int ri = 0; ri < 4; ++ri)
    #pragma unroll
    for (int c = 0; c < 2; ++c) acc[ri][c] = (f32x4){0.f, 0.f, 0.f, 0.f};

  for (int kb = 0; kb < DH / 32; ++kb) {
    { // A tile 64x32 = 256 chunks: 1 issue per wave
      int L = wave * 64 + lane;
      int g = swz(L);
      int n = g >> 2, c4 = g & 3;
      int gm = m0 + n; if (gm >= NN) gm = NN - 1;
      load_lds16(A + (size_t)gm * DH + kb * 32 + c4 * 8, (char*)As + wave * 1024);
    }
    { // B panel 128x32 = 512 chunks: 2 issues per wave
      const short* __restrict__ panel = P + (size_t)kb * (NCLS * 32);
      #pragma unroll
      for (int u = 0; u < 2; ++u) {
        int L = wave * 128 + u * 64 + lane;
        int g = swz(L);
        load_lds16(panel + (size_t)g * 8, (char*)Bs + (wave * 128 + u * 64) * 16);
      }
    }
    __syncthreads();
    short8_t a[4];
    #pragma unroll
    for (int ri = 0; ri < 4; ++ri) {
      int n = ri * 16 + llo;
      int slot = n * 4 + (lhi ^ ((n >> 1) & 3));
      a[ri] = *(const short8_t*)(As + slot * 8);
    }
    #pragma unroll
    for (int c = 0; c < 2; ++c) {
      int n = wcol0 + c * 16 + llo;
      int slot = n * 4 + (lhi ^ ((n >> 1) & 3));
      short8_t bfr = *(const short8_t*)(Bs + slot * 8);
      #pragma unroll
      for (int ri = 0; ri < 4; ++ri)
        acc[ri][c] = __builtin_amdgcn_mfma_f32_16x16x32_bf16(a[ri], bfr, acc[ri][c], 0, 0, 0);
    }
    __syncthreads();
  }

  #pragma unroll
  for (int c = 0; c < 2; ++c) {
    int col = wcol0 + c * 16 + llo;
    float bc = bias[col];
    #pragma unroll
    for (int ri = 0; ri < 4; ++ri)
      #pragma unroll
      for (int r = 0; r < 4; ++r) {
        int gm = m0 + ri * 16 + lhi * 4 + r;
        if (gm < NN) C[(size_t)gm * NCLS + col] = acc[ri][c][r] + bc;
      }
  }
}

extern "C" void kernel_launch(void* const* d_in, const int* in_sizes, int n_in,
                              void* d_out, int out_size, void* d_ws, size_t ws_size,
                              hipStream_t stream) {
  (void)in_sizes; (void)n_in; (void)out_size; (void)ws_size;
  const float* x      = (const float*)d_in[0];
  const int*   ei     = (const int*)  d_in[1];
  const float* pos    = (const float*)d_in[2];
  const float* Wrel1  = (const float*)d_in[3];
  const float* brel1  = (const float*)d_in[4];
  const float* Wroot1 = (const float*)d_in[5];
  const float* g1     = (const float*)d_in[6];
  const float* b1     = (const float*)d_in[7];
  const float* Wrel2  = (const float*)d_in[8];
  const float* brel2  = (const float*)d_in[9];
  const float* Wroot2 = (const float*)d_in[10];
  const float* g2     = (const float*)d_in[11];
  const float* b2     = (const float*)d_in[12];
  const float* Wcls   = (const float*)d_in[13];
  const float* bcls   = (const float*)d_in[14];
  const int* src = ei;           // edge_index[0]
  const int* dst = ei + NE;      // edge_index[1]
  float* out = (float*)d_out;

  char* ws = (char*)d_ws;
  size_t off = 0;
  auto alloc = [&](size_t bytes) -> void* {
    void* p = ws + off;
    off += (bytes + 255) & ~(size_t)255;
    return p;
  };
  float*           ew     = (float*)          alloc((size_t)NE * 4);
  int*             rowptr = (int*)            alloc((size_t)(NN + 1) * 4);
  int*             cnt    = (int*)            alloc((size_t)NN * 4);
  int2*            glist  = (int2*)           alloc((size_t)NE * 8);
  __hip_bfloat16*  agg1   = (__hip_bfloat16*) alloc((size_t)NN * DIN * 2);
  __hip_bfloat16*  h1     = (__hip_bfloat16*) alloc((size_t)NN * DH * 2);
  __hip_bfloat16*  agg2   = (__hip_bfloat16*) alloc((size_t)NN * DH * 2);
  __hip_bfloat16*  h2     = agg2;             // layer-2 GEMM writes in place
  short*           xb     = (short*)agg2;     // bf16 x, overlaps agg2 (see ordering)
  short*           Pr1    = (short*)alloc((size_t)DH * DIN * 2);
  short*           Pq1    = (short*)alloc((size_t)DH * DIN * 2);
  short*           Pr2    = (short*)alloc((size_t)DH * DH * 2);
  short*           Pq2    = (short*)alloc((size_t)DH * DH * 2);
  short*           Pc     = (short*)alloc((size_t)NCLS * DH * 2);

  // ---- weight packing + x conversion ----
  k_pack_w<<<(DH * DIN + 255) / 256, 256, 0, stream>>>(Wrel1,  Pr1, DH,   DIN);
  k_pack_w<<<(DH * DIN + 255) / 256, 256, 0, stream>>>(Wroot1, Pq1, DH,   DIN);
  k_pack_w<<<(DH * DH  + 255) / 256, 256, 0, stream>>>(Wrel2,  Pr2, DH,   DH);
  k_pack_w<<<(DH * DH  + 255) / 256, 256, 0, stream>>>(Wroot2, Pq2, DH,   DH);
  k_pack_w<<<(NCLS * DH + 255) / 256, 256, 0, stream>>>(Wcls,  Pc,  NCLS, DH);
  k_cvt_x<<<(NN * DIN / 8 + 255) / 256, 256, 0, stream>>>(x, xb);

  // ---- CSR build (glist = {src, ew} records, no perm indirection) ----
  k_zero<<<(NN + 255) / 256, 256, 0, stream>>>(cnt, NN);
  k_ew_hist<<<(NE + 255) / 256, 256, 0, stream>>>(src, dst, pos, ew, cnt);
  k_scan<<<1, 256, 0, stream>>>(cnt, rowptr, NN);
  k_zero<<<(NN + 255) / 256, 256, 0, stream>>>(cnt, NN);
  k_scatter<<<(NE + 255) / 256, 256, 0, stream>>>(src, dst, ew, rowptr, cnt, glist);

  int gblocks = (NN + TBM - 1) / TBM;
  int ablocks = (NN + 3) / 4;

  // ---- layer 1 (agg1 gathers from bf16 xb) ----
  k_agg1<<<ablocks, 256, 0, stream>>>(rowptr, glist, xb, agg1);
  k_mfma_ln<<<gblocks, 512, 0, stream>>>((const short*)agg1, Pr1,
                                         xb, Pq1,
                                         brel1, g1, b1, h1, DIN);
  // ---- layer 2 (xb dead from here; agg2 reuses its space) ----
  k_agg2<<<ablocks, 256, 0, stream>>>(rowptr, glist, (const short*)h1, agg2);
  k_mfma_ln<<<gblocks, 512, 0, stream>>>((const short*)agg2, Pr2,
                                         (const short*)h1, Pq2,
                                         brel2, g2, b2, h2, DH);
  // ---- classifier ----
  k_mfma_cls<<<(NN + CBM - 1) / CBM, 256, 0, stream>>>((const short*)h2, Pc, bcls, out);
}

// Round 9
// 397.153 us; speedup vs baseline: 4.1973x; 1.2875x over previous
//
#include <hip/hip_runtime.h>
#include <hip/hip_bf16.h>
#include <cstdint>
#include <cstddef>

#define NN   50000
#define NE   400000
#define DIN  128
#define DH   512
#define NCLS 128

#define NSCB ((NN + 255) / 256)   // scan blocks = 196

#define NEG_INF (-__builtin_inff())

typedef short short8_t __attribute__((ext_vector_type(8)));
typedef float f32x4   __attribute__((ext_vector_type(4)));

typedef const __attribute__((address_space(1))) void* gas_t;
typedef __attribute__((address_space(3))) void* las_t;

// DMA 16B/lane: LDS dest = wave-uniform base + lane*16 (linear); global src per-lane.
static __device__ inline void load_lds16(const void* g, void* l) {
  __builtin_amdgcn_global_load_lds((gas_t)g, (las_t)l, 16, 0, 0);
}

// chunk swizzle (involution): LDS slot L <-> global chunk g
static __device__ inline int swz(int L) {
  return (L & ~3) | ((L & 3) ^ ((L >> 3) & 3));
}

static __device__ inline short f2bf(float f) {
  __hip_bfloat16 h = __float2bfloat16(f);
  return *reinterpret_cast<short*>(&h);
}

static __device__ inline float bf2f(short s) {
  unsigned int u = ((unsigned int)(unsigned short)s) << 16;
  return __uint_as_float(u);
}

// block-wide exclusive scan helper (256 threads): returns exclusive prefix, total via ref
static __device__ inline int block_scan_excl(int v, int tid, int* total) {
  __shared__ int warp_sums[4];
  int xinc = v;
  #pragma unroll
  for (int o = 1; o < 64; o <<= 1) {
    int t = __shfl_up(xinc, o);
    if ((tid & 63) >= o) xinc += t;
  }
  int wid = tid >> 6;
  if ((tid & 63) == 63) warp_sums[wid] = xinc;
  __syncthreads();
  int woff = 0;
  #pragma unroll
  for (int w = 0; w < 4; ++w) if (w < wid) woff += warp_sums[w];
  int tot = warp_sums[0] + warp_sums[1] + warp_sums[2] + warp_sums[3];
  if (total) *total = tot;
  return xinc + woff - v;
}

// ---------------- zero an int buffer ----------------
__launch_bounds__(256)
__global__ void k_zero(int* __restrict__ p, int n) {
  int i = blockIdx.x * 256 + threadIdx.x;
  if (i < n) p[i] = 0;
}

// ---------------- x fp32 -> bf16 (row-major unchanged) ----------------
__launch_bounds__(256)
__global__ void k_cvt_x(const float* __restrict__ x, short* __restrict__ xb) {
  int i = blockIdx.x * 256 + threadIdx.x;
  if ((size_t)i * 8 >= (size_t)NN * DIN) return;
  float4 f0 = *(const float4*)(x + (size_t)i * 8);
  float4 f1 = *(const float4*)(x + (size_t)i * 8 + 4);
  short8_t v;
  v[0] = f2bf(f0.x); v[1] = f2bf(f0.y); v[2] = f2bf(f0.z); v[3] = f2bf(f0.w);
  v[4] = f2bf(f1.x); v[5] = f2bf(f1.y); v[6] = f2bf(f1.z); v[7] = f2bf(f1.w);
  *(short8_t*)(xb + (size_t)i * 8) = v;
}

// ---------------- pack fp32 weight [N][K] -> bf16 K-panels P[kb][n][32] ----------------
__launch_bounds__(256)
__global__ void k_pack_w(const float* __restrict__ W, short* __restrict__ P,
                         int N, int K) {
  int id = blockIdx.x * 256 + threadIdx.x;
  int total = N * K;
  if (id >= total) return;
  int kb  = id / (N * 32);
  int rem = id % (N * 32);
  int n   = rem / 32;
  int kk  = rem % 32;
  P[id] = f2bf(W[(size_t)n * K + kb * 32 + kk]);
}

// ---------------- edge weights + in-degree histogram ----------------
__launch_bounds__(256)
__global__ void k_ew_hist(const int* __restrict__ src, const int* __restrict__ dst,
                          const float* __restrict__ pos, float* __restrict__ ew,
                          int* __restrict__ deg) {
  int e = blockIdx.x * 256 + threadIdx.x;
  if (e >= NE) return;
  int s = src[e], d = dst[e];
  ew[e] = 1.0f / (pos[s] - pos[d]);
  atomicAdd(&deg[d], 1);
}

// ---------------- multi-block exclusive scan, phase a: local scan ----------------
__launch_bounds__(256)
__global__ void k_scan_local(const int* __restrict__ deg, int* __restrict__ rowptr,
                             int* __restrict__ bsum) {
  int tid = threadIdx.x;
  int idx = blockIdx.x * 256 + tid;
  int v = (idx < NN) ? deg[idx] : 0;
  int total;
  int ex = block_scan_excl(v, tid, &total);
  if (idx < NN) rowptr[idx] = ex;
  if (tid == 0) bsum[blockIdx.x] = total;
}

// ---------------- phase b: scan the block sums (1 block), write rowptr[NN] ----------
__launch_bounds__(256)
__global__ void k_scan_bsums(int* __restrict__ bsum, int* __restrict__ rowptr) {
  int tid = threadIdx.x;
  int v = (tid < NSCB) ? bsum[tid] : 0;
  int total;
  int ex = block_scan_excl(v, tid, &total);
  if (tid < NSCB) bsum[tid] = ex;
  if (tid == 0) rowptr[NN] = total;
}

// ---------------- phase c: add block offsets ----------------
__launch_bounds__(256)
__global__ void k_scan_add(const int* __restrict__ bsum, int* __restrict__ rowptr) {
  int idx = blockIdx.x * 256 + threadIdx.x;
  if (idx < NN) rowptr[idx] += bsum[blockIdx.x];
}

// ---------------- scatter {src, ew} records into CSR slots ----------------
__launch_bounds__(256)
__global__ void k_scatter(const int* __restrict__ src, const int* __restrict__ dst,
                          const float* __restrict__ ew, const int* __restrict__ rowptr,
                          int* __restrict__ cnt, int2* __restrict__ glist) {
  int e = blockIdx.x * 256 + threadIdx.x;
  if (e >= NE) return;
  int d = dst[e];
  int p = atomicAdd(&cnt[d], 1);
  glist[rowptr[d] + p] = make_int2(src[e], __float_as_int(ew[e]));
}

// ---------------- layer-1 aggregation: wave/node, bf16 x rows (256B) ----------------
__launch_bounds__(256)
__global__ void k_agg1(const int* __restrict__ rowptr, const int2* __restrict__ glist,
                       const short* __restrict__ xb, __hip_bfloat16* __restrict__ agg) {
  int node = blockIdx.x * 4 + (threadIdx.x >> 6);
  int lane = threadIdx.x & 63;
  if (node >= NN) return;
  int beg = rowptr[node], end = rowptr[node + 1];
  float a0 = NEG_INF, a1 = NEG_INF;
  int i = beg;
  for (; i + 2 <= end; i += 2) {
    int2 m0 = glist[i], m1 = glist[i + 1];
    __hip_bfloat162 v0 = *(const __hip_bfloat162*)(xb + (size_t)m0.x * DIN + lane * 2);
    __hip_bfloat162 v1 = *(const __hip_bfloat162*)(xb + (size_t)m1.x * DIN + lane * 2);
    float w0 = __int_as_float(m0.y), w1 = __int_as_float(m1.y);
    float2 f0 = __bfloat1622float2(v0);
    float2 f1 = __bfloat1622float2(v1);
    a0 = fmaxf(a0, fmaxf(f0.x * w0, f1.x * w1));
    a1 = fmaxf(a1, fmaxf(f0.y * w0, f1.y * w1));
  }
  if (i < end) {
    int2 m0 = glist[i];
    __hip_bfloat162 v0 = *(const __hip_bfloat162*)(xb + (size_t)m0.x * DIN + lane * 2);
    float w0 = __int_as_float(m0.y);
    float2 f0 = __bfloat1622float2(v0);
    a0 = fmaxf(a0, f0.x * w0);
    a1 = fmaxf(a1, f0.y * w0);
  }
  if (beg == end) { a0 = 0.0f; a1 = 0.0f; }   // PyG: empty segments -> 0
  *(__hip_bfloat162*)(agg + (size_t)node * DIN + lane * 2) =
      __float22bfloat162_rn(make_float2(a0, a1));
}

// ---------------- layer-2 aggregation: wave/node, 16B/lane rows (1KB) ----------------
__launch_bounds__(256)
__global__ void k_agg2(const int* __restrict__ rowptr, const int2* __restrict__ glist,
                       const short* __restrict__ h, __hip_bfloat16* __restrict__ agg) {
  int node = blockIdx.x * 4 + (threadIdx.x >> 6);
  int lane = threadIdx.x & 63;
  if (node >= NN) return;
  int beg = rowptr[node], end = rowptr[node + 1];
  float acc[8];
  #pragma unroll
  for (int j = 0; j < 8; ++j) acc[j] = NEG_INF;
  int i = beg;
  for (; i + 2 <= end; i += 2) {
    int2 m0 = glist[i], m1 = glist[i + 1];
    short8_t v0 = *(const short8_t*)(h + (size_t)m0.x * DH + lane * 8);
    short8_t v1 = *(const short8_t*)(h + (size_t)m1.x * DH + lane * 8);
    float w0 = __int_as_float(m0.y), w1 = __int_as_float(m1.y);
    #pragma unroll
    for (int j = 0; j < 8; ++j)
      acc[j] = fmaxf(acc[j], fmaxf(bf2f(v0[j]) * w0, bf2f(v1[j]) * w1));
  }
  if (i < end) {
    int2 m0 = glist[i];
    short8_t v0 = *(const short8_t*)(h + (size_t)m0.x * DH + lane * 8);
    float w0 = __int_as_float(m0.y);
    #pragma unroll
    for (int j = 0; j < 8; ++j)
      acc[j] = fmaxf(acc[j], bf2f(v0[j]) * w0);
  }
  if (beg == end) {
    #pragma unroll
    for (int j = 0; j < 8; ++j) acc[j] = 0.0f;
  }
  short8_t o;
  #pragma unroll
  for (int j = 0; j < 8; ++j) o[j] = f2bf(acc[j]);
  *(short8_t*)((short*)agg + (size_t)node * DH + lane * 8) = o;
}

// ============== MFMA fused dual GEMM + bias + LayerNorm + ReLU -> bf16 ==============
// out[m,:] = relu( LN( A0[m,:]@W0^T + A1[m,:]@W1^T + brel ) * g + b ), bf16.
// A0/A1: [M,K] bf16 row-major. P0/P1: packed bf16 panels P[kb][n(0..511)][32].
// Tile: BM=64 x BN=512 (full row). 512 threads = 8 waves; wave w owns cols w*64..+63.
#define TBM 64

__launch_bounds__(512)
__global__ void k_mfma_ln(const short* __restrict__ A0, const short* __restrict__ P0,
                          const short* __restrict__ A1, const short* __restrict__ P1,
                          const float* __restrict__ brel, const float* __restrict__ gvec,
                          const float* __restrict__ bvec,
                          __hip_bfloat16* __restrict__ out, int K) {
  __shared__ __align__(16) short Bs[DH * 32];    // 32 KB
  __shared__ __align__(16) short As[TBM * 32];   // 4 KB
  __shared__ float2 red[8][TBM];                 // 4 KB

  int tid  = threadIdx.x;
  int wave = tid >> 6;                 // 0..7
  int lane = tid & 63;
  int lhi  = lane >> 4;                // k-chunk selector
  int llo  = lane & 15;                // fragment row (A) / col (B,D)
  int wcol0 = wave * 64;
  int m0 = blockIdx.x * TBM;

  f32x4 acc[4][4];
  #pragma unroll
  for (int ri = 0; ri < 4; ++ri)
    #pragma unroll
    for (int c = 0; c < 4; ++c) acc[ri][c] = (f32x4){0.f, 0.f, 0.f, 0.f};

  for (int pass = 0; pass < 2; ++pass) {
    const short* __restrict__ Aop = pass ? A1 : A0;
    const short* __restrict__ P   = pass ? P1 : P0;
    int nkb = K >> 5;
    for (int kb = 0; kb < nkb; ++kb) {
      // ---- A tile 64x32 = 256 chunks: 1 DMA issue on waves 0..3 ----
      if (wave < 4) {
        int L = wave * 64 + lane;
        int g = swz(L);
        int n = g >> 2, c4 = g & 3;
        int gm = m0 + n; if (gm >= NN) gm = NN - 1;
        load_lds16(Aop + (size_t)gm * K + kb * 32 + c4 * 8,
                   (char*)As + wave * 1024);
      }
      // ---- B panel 512x32 = 2048 chunks: 4 DMA issues per wave ----
      const short* __restrict__ panel = P + (size_t)kb * (DH * 32);
      #pragma unroll
      for (int u = 0; u < 4; ++u) {
        int L = wave * 256 + u * 64 + lane;
        int g = swz(L);
        load_lds16(panel + (size_t)g * 8, (char*)Bs + (wave * 256 + u * 64) * 16);
      }
      __syncthreads();                 // drains vmcnt -> DMA complete
      // ---- fragments + 16 MFMAs ----
      short8_t a[4];
      #pragma unroll
      for (int ri = 0; ri < 4; ++ri) {
        int n = ri * 16 + llo;
        int slot = n * 4 + (lhi ^ ((n >> 1) & 3));
        a[ri] = *(const short8_t*)(As + slot * 8);
      }
      #pragma unroll
      for (int c = 0; c < 4; ++c) {
        int n = wcol0 + c * 16 + llo;
        int slot = n * 4 + (lhi ^ ((n >> 1) & 3));
        short8_t bfr = *(const short8_t*)(Bs + slot * 8);
        #pragma unroll
        for (int ri = 0; ri < 4; ++ri)
          acc[ri][c] = __builtin_amdgcn_mfma_f32_16x16x32_bf16(a[ri], bfr, acc[ri][c], 0, 0, 0);
      }
      __syncthreads();
    }
  }

  // ---- epilogue: bias, LN (cross-wave via LDS), scale/shift, relu, bf16 store ----
  float brv[4], gv[4], bev[4];
  #pragma unroll
  for (int c = 0; c < 4; ++c) {
    int col = wcol0 + c * 16 + llo;
    brv[c] = brel[col];
    gv[c]  = gvec[col];
    bev[c] = bvec[col];
  }
  #pragma unroll
  for (int ri = 0; ri < 4; ++ri)
    #pragma unroll
    for (int r = 0; r < 4; ++r) {
      float t = 0.f, tt = 0.f;
      #pragma unroll
      for (int c = 0; c < 4; ++c) {
        float v = acc[ri][c][r] + brv[c];
        t += v; tt += v * v;
      }
      #pragma unroll
      for (int o = 1; o < 16; o <<= 1) {
        t  += __shfl_xor(t, o);
        tt += __shfl_xor(tt, o);
      }
      if (llo == 0) red[wave][ri * 16 + lhi * 4 + r] = make_float2(t, tt);
    }
  __syncthreads();
  if (tid < TBM) {
    float S = 0.f, SS = 0.f;
    #pragma unroll
    for (int w = 0; w < 8; ++w) { float2 p = red[w][tid]; S += p.x; SS += p.y; }
    float mean = S * (1.0f / DH);
    float var  = SS * (1.0f / DH) - mean * mean;
    red[0][tid] = make_float2(mean, rsqrtf(var + 1e-5f));
  }
  __syncthreads();
  #pragma unroll
  for (int ri = 0; ri < 4; ++ri)
    #pragma unroll
    for (int r = 0; r < 4; ++r) {
      int row = ri * 16 + lhi * 4 + r;
      int gm = m0 + row;
      if (gm < NN) {
        float2 mr = red[0][row];
        #pragma unroll
        for (int c = 0; c < 4; ++c) {
          float v = acc[ri][c][r] + brv[c];
          float o = fmaxf((v - mr.x) * mr.y * gv[c] + bev[c], 0.0f);
          out[(size_t)gm * DH + wcol0 + c * 16 + llo] = __float2bfloat16(o);
        }
      }
    }
}

// ============== MFMA classifier GEMM: out = h2 @ Wcls^T + bcls (fp32) ==============
// BM=64 x BN=128, BK=32, 256 threads = 4 waves; wave w owns cols w*32..+31.
#define CBM 64

__launch_bounds__(256)
__global__ void k_mfma_cls(const short* __restrict__ A, const short* __restrict__ P,
                           const float* __restrict__ bias, float* __restrict__ C) {
  __shared__ __align__(16) short Bs[NCLS * 32];  // 8 KB
  __shared__ __align__(16) short As[CBM * 32];   // 4 KB

  int tid  = threadIdx.x;
  int wave = tid >> 6;
  int lane = tid & 63;
  int lhi  = lane >> 4;
  int llo  = lane & 15;
  int wcol0 = wave * 32;
  int m0 = blockIdx.x * CBM;

  f32x4 acc[4][2];
  #pragma unroll
  for (int ri = 0; ri < 4; ++ri)
    #pragma unroll
    for (int c = 0; c < 2; ++c) acc[ri][c] = (f32x4){0.f, 0.f, 0.f, 0.f};

  for (int kb = 0; kb < DH / 32; ++kb) {
    { // A tile 64x32 = 256 chunks: 1 issue per wave
      int L = wave * 64 + lane;
      int g = swz(L);
      int n = g >> 2, c4 = g & 3;
      int gm = m0 + n; if (gm >= NN) gm = NN - 1;
      load_lds16(A + (size_t)gm * DH + kb * 32 + c4 * 8, (char*)As + wave * 1024);
    }
    { // B panel 128x32 = 512 chunks: 2 issues per wave
      const short* __restrict__ panel = P + (size_t)kb * (NCLS * 32);
      #pragma unroll
      for (int u = 0; u < 2; ++u) {
        int L = wave * 128 + u * 64 + lane;
        int g = swz(L);
        load_lds16(panel + (size_t)g * 8, (char*)Bs + (wave * 128 + u * 64) * 16);
      }
    }
    __syncthreads();
    short8_t a[4];
    #pragma unroll
    for (int ri = 0; ri < 4; ++ri) {
      int n = ri * 16 + llo;
      int slot = n * 4 + (lhi ^ ((n >> 1) & 3));
      a[ri] = *(const short8_t*)(As + slot * 8);
    }
    #pragma unroll
    for (int c = 0; c < 2; ++c) {
      int n = wcol0 + c * 16 + llo;
      int slot = n * 4 + (lhi ^ ((n >> 1) & 3));
      short8_t bfr = *(const short8_t*)(Bs + slot * 8);
      #pragma unroll
      for (int ri = 0; ri < 4; ++ri)
        acc[ri][c] = __builtin_amdgcn_mfma_f32_16x16x32_bf16(a[ri], bfr, acc[ri][c], 0, 0, 0);
    }
    __syncthreads();
  }

  #pragma unroll
  for (int c = 0; c < 2; ++c) {
    int col = wcol0 + c * 16 + llo;
    float bc = bias[col];
    #pragma unroll
    for (int ri = 0; ri < 4; ++ri)
      #pragma unroll
      for (int r = 0; r < 4; ++r) {
        int gm = m0 + ri * 16 + lhi * 4 + r;
        if (gm < NN) C[(size_t)gm * NCLS + col] = acc[ri][c][r] + bc;
      }
  }
}

extern "C" void kernel_launch(void* const* d_in, const int* in_sizes, int n_in,
                              void* d_out, int out_size, void* d_ws, size_t ws_size,
                              hipStream_t stream) {
  (void)in_sizes; (void)n_in; (void)out_size; (void)ws_size;
  const float* x      = (const float*)d_in[0];
  const int*   ei     = (const int*)  d_in[1];
  const float* pos    = (const float*)d_in[2];
  const float* Wrel1  = (const float*)d_in[3];
  const float* brel1  = (const float*)d_in[4];
  const float* Wroot1 = (const float*)d_in[5];
  const float* g1     = (const float*)d_in[6];
  const float* b1     = (const float*)d_in[7];
  const float* Wrel2  = (const float*)d_in[8];
  const float* brel2  = (const float*)d_in[9];
  const float* Wroot2 = (const float*)d_in[10];
  const float* g2     = (const float*)d_in[11];
  const float* b2     = (const float*)d_in[12];
  const float* Wcls   = (const float*)d_in[13];
  const float* bcls   = (const float*)d_in[14];
  const int* src = ei;           // edge_index[0]
  const int* dst = ei + NE;      // edge_index[1]
  float* out = (float*)d_out;

  char* ws = (char*)d_ws;
  size_t off = 0;
  auto alloc = [&](size_t bytes) -> void* {
    void* p = ws + off;
    off += (bytes + 255) & ~(size_t)255;
    return p;
  };
  float*           ew     = (float*)          alloc((size_t)NE * 4);
  int*             rowptr = (int*)            alloc((size_t)(NN + 1) * 4);
  int*             cnt    = (int*)            alloc((size_t)NN * 4);
  int*             bsum   = (int*)            alloc((size_t)256 * 4);
  int2*            glist  = (int2*)           alloc((size_t)NE * 8);
  __hip_bfloat16*  agg1   = (__hip_bfloat16*) alloc((size_t)NN * DIN * 2);
  __hip_bfloat16*  h1     = (__hip_bfloat16*) alloc((size_t)NN * DH * 2);
  __hip_bfloat16*  agg2   = (__hip_bfloat16*) alloc((size_t)NN * DH * 2);
  __hip_bfloat16*  h2     = agg2;             // layer-2 GEMM writes in place
  short*           xb     = (short*)agg2;     // bf16 x, overlaps agg2 (see ordering)
  short*           Pr1    = (short*)alloc((size_t)DH * DIN * 2);
  short*           Pq1    = (short*)alloc((size_t)DH * DIN * 2);
  short*           Pr2    = (short*)alloc((size_t)DH * DH * 2);
  short*           Pq2    = (short*)alloc((size_t)DH * DH * 2);
  short*           Pc     = (short*)alloc((size_t)NCLS * DH * 2);

  // ---- weight packing + x conversion ----
  k_pack_w<<<(DH * DIN + 255) / 256, 256, 0, stream>>>(Wrel1,  Pr1, DH,   DIN);
  k_pack_w<<<(DH * DIN + 255) / 256, 256, 0, stream>>>(Wroot1, Pq1, DH,   DIN);
  k_pack_w<<<(DH * DH  + 255) / 256, 256, 0, stream>>>(Wrel2,  Pr2, DH,   DH);
  k_pack_w<<<(DH * DH  + 255) / 256, 256, 0, stream>>>(Wroot2, Pq2, DH,   DH);
  k_pack_w<<<(NCLS * DH + 255) / 256, 256, 0, stream>>>(Wcls,  Pc,  NCLS, DH);
  k_cvt_x<<<(NN * DIN / 8 + 255) / 256, 256, 0, stream>>>(x, xb);

  // ---- CSR build (multi-block scan) ----
  k_zero<<<(NN + 255) / 256, 256, 0, stream>>>(cnt, NN);
  k_ew_hist<<<(NE + 255) / 256, 256, 0, stream>>>(src, dst, pos, ew, cnt);
  k_scan_local<<<NSCB, 256, 0, stream>>>(cnt, rowptr, bsum);
  k_scan_bsums<<<1, 256, 0, stream>>>(bsum, rowptr);
  k_scan_add<<<NSCB, 256, 0, stream>>>(bsum, rowptr);
  k_zero<<<(NN + 255) / 256, 256, 0, stream>>>(cnt, NN);
  k_scatter<<<(NE + 255) / 256, 256, 0, stream>>>(src, dst, ew, rowptr, cnt, glist);

  int gblocks = (NN + TBM - 1) / TBM;
  int ablocks = (NN + 3) / 4;

  // ---- layer 1 (agg1 gathers from bf16 xb) ----
  k_agg1<<<ablocks, 256, 0, stream>>>(rowptr, glist, xb, agg1);
  k_mfma_ln<<<gblocks, 512, 0, stream>>>((const short*)agg1, Pr1,
                                         xb, Pq1,
                                         brel1, g1, b1, h1, DIN);
  // ---- layer 2 (xb dead from here; agg2 reuses its space) ----
  k_agg2<<<ablocks, 256, 0, stream>>>(rowptr, glist, (const short*)h1, agg2);
  k_mfma_ln<<<gblocks, 512, 0, stream>>>((const short*)agg2, Pr2,
                                         (const short*)h1, Pq2,
                                         brel2, g2, b2, h2, DH);
  // ---- classifier ----
  k_mfma_cls<<<(NN + CBM - 1) / CBM, 256, 0, stream>>>((const short*)h2, Pc, bcls, out);
}